// Round 2
// baseline (1128.997 us; speedup 1.0000x reference)
//
#include <hip/hip_runtime.h>
#include <hip/hip_bf16.h>

// Problem constants
constexpr int B_  = 2;
constexpr int L_  = 1024;
constexpr int DIN = 1024;
constexpr int DM  = 2048;
constexpr int DS  = 16;
constexpr int DR  = 128;
constexpr int KC  = 4;       // conv kernel size
constexpr int M_  = B_ * L_; // 2048 rows

typedef __bf16 bf16x8 __attribute__((ext_vector_type(8)));
typedef float  f32x4  __attribute__((ext_vector_type(4)));

// ---------------------------------------------------------------------------
// f32 -> bf16 elementwise convert (for MFMA A-operands)
// ---------------------------------------------------------------------------
__global__ void convert_f32_bf16(const float* __restrict__ in, __bf16* __restrict__ out, int n) {
    int i = blockIdx.x * 256 + threadIdx.x;
    if (i < n) out[i] = (__bf16)in[i];
}

// ---------------------------------------------------------------------------
// f32 transpose + bf16 convert: in (R x C) f32 -> out (C x R) bf16.
// R, C divisible by 32. Block (32,8).
// ---------------------------------------------------------------------------
__global__ void transpose_f32_bf16(const float* __restrict__ in, __bf16* __restrict__ out,
                                   int R, int C) {
    __shared__ float tile[32][33];
    int bx = blockIdx.x * 32, by = blockIdx.y * 32;
    int tx = threadIdx.x, ty = threadIdx.y; // (32, 8)
    #pragma unroll
    for (int j = 0; j < 32; j += 8) {
        tile[ty + j][tx] = in[(size_t)(by + ty + j) * C + (bx + tx)];
    }
    __syncthreads();
    #pragma unroll
    for (int j = 0; j < 32; j += 8) {
        out[(size_t)(bx + ty + j) * R + (by + tx)] = (__bf16)tile[tx][ty + j];
    }
}

// ---------------------------------------------------------------------------
// MFMA bf16 GEMM: C(MxN) = A(MxK) @ B(KxN), with BT = B^T (N x K) row-major,
// both bf16; output f32. Wave computes 32x32 via 2x2 mfma_f32_16x16x32_bf16;
// block = 4 waves = 64x64 tile.
// A-frag: A[m=lane&15][k=quad*8+j]; B-frag: BT[n=lane&15][k=quad*8+j];
// C/D: col=lane&15, row=quad*4+reg.
// ---------------------------------------------------------------------------
__global__ void gemm_mfma(const __bf16* __restrict__ A, const __bf16* __restrict__ BT,
                          float* __restrict__ Cout, int M, int N, int K) {
    int lane = threadIdx.x & 63;
    int wave = threadIdx.x >> 6;        // 0..3
    int wm = wave >> 1, wn = wave & 1;
    int m0 = blockIdx.y * 64 + wm * 32;
    int n0 = blockIdx.x * 64 + wn * 32;
    int quad = lane >> 4, r = lane & 15;

    f32x4 acc[2][2] = {};

    const __bf16* a0p = A  + (size_t)(m0 +      r) * K + quad * 8;
    const __bf16* a1p = A  + (size_t)(m0 + 16 + r) * K + quad * 8;
    const __bf16* b0p = BT + (size_t)(n0 +      r) * K + quad * 8;
    const __bf16* b1p = BT + (size_t)(n0 + 16 + r) * K + quad * 8;

    for (int k0 = 0; k0 < K; k0 += 32) {
        bf16x8 a0 = *(const bf16x8*)(a0p + k0);
        bf16x8 a1 = *(const bf16x8*)(a1p + k0);
        bf16x8 b0 = *(const bf16x8*)(b0p + k0);
        bf16x8 b1 = *(const bf16x8*)(b1p + k0);
        acc[0][0] = __builtin_amdgcn_mfma_f32_16x16x32_bf16(a0, b0, acc[0][0], 0, 0, 0);
        acc[0][1] = __builtin_amdgcn_mfma_f32_16x16x32_bf16(a0, b1, acc[0][1], 0, 0, 0);
        acc[1][0] = __builtin_amdgcn_mfma_f32_16x16x32_bf16(a1, b0, acc[1][0], 0, 0, 0);
        acc[1][1] = __builtin_amdgcn_mfma_f32_16x16x32_bf16(a1, b1, acc[1][1], 0, 0, 0);
    }

    #pragma unroll
    for (int im = 0; im < 2; im++) {
        #pragma unroll
        for (int in_ = 0; in_ < 2; in_++) {
            int col = n0 + in_ * 16 + r;
            #pragma unroll
            for (int j = 0; j < 4; j++) {
                int row = m0 + im * 16 + quad * 4 + j;
                Cout[(size_t)row * N + col] = acc[im][in_][j];
            }
        }
    }
}

// ---------------------------------------------------------------------------
// Causal depthwise conv (K=4) + bias + SiLU. x (B,L,DM) f32 -> xc f32.
// ---------------------------------------------------------------------------
__global__ void conv_silu(const float* __restrict__ x, const float* __restrict__ w,
                          const float* __restrict__ bias, float* __restrict__ xc) {
    int idx = blockIdx.x * 256 + threadIdx.x;     // 0 .. B*L*DM
    int d  = idx % DM;
    int bl = idx / DM;
    int l  = bl % L_;
    float acc = bias[d];
    #pragma unroll
    for (int i = 0; i < KC; i++) {
        int li = l - (KC - 1) + i;
        if (li >= 0) acc += x[idx + (i - (KC - 1)) * DM] * w[d * KC + i];
    }
    xc[idx] = acc / (1.f + __expf(-acc));
}

// ---------------------------------------------------------------------------
// Fused projections: Bp = xc@W_B, Cp = xc@W_C, dtmp = xc@W_dt.
// One block per row; 160 active threads each own one output column.
// ---------------------------------------------------------------------------
__global__ void proj_fused(const float* __restrict__ xc,
                           const float* __restrict__ W_B, const float* __restrict__ W_C,
                           const float* __restrict__ W_dt,
                           float* __restrict__ Bp, float* __restrict__ Cp,
                           float* __restrict__ dtmp) {
    int row = blockIdx.x;   // 0..M_-1
    int t = threadIdx.x;    // 256
    __shared__ float sx[256];

    const float* Wp; int ldw, col;
    if (t < 16)       { Wp = W_B;  ldw = DS; col = t; }
    else if (t < 32)  { Wp = W_C;  ldw = DS; col = t - 16; }
    else if (t < 160) { Wp = W_dt; ldw = DR; col = t - 32; }
    else              { Wp = W_B;  ldw = 0;  col = 0; }

    const float* xr = xc + (size_t)row * DM;
    float acc = 0.f;
    for (int c0 = 0; c0 < DM; c0 += 256) {
        sx[t] = xr[c0 + t];
        __syncthreads();
        #pragma unroll 8
        for (int j = 0; j < 256; j++) {
            acc += sx[j] * Wp[(size_t)(c0 + j) * ldw + col];
        }
        __syncthreads();
    }
    if (t < 16)       Bp[(size_t)row * DS + t]          = acc;
    else if (t < 32)  Cp[(size_t)row * DS + (t - 16)]   = acc;
    else if (t < 160) dtmp[(size_t)row * DR + (t - 32)] = acc;
}

// ---------------------------------------------------------------------------
// delta = softplus(dtmp @ dt_w + dt_b). dtmp (M,DR), dt_w (DR,DM), all f32.
// ---------------------------------------------------------------------------
__global__ void delta_kernel(const float* __restrict__ dtmp, const float* __restrict__ dt_w,
                             const float* __restrict__ dt_b, float* __restrict__ delta) {
    int n   = blockIdx.x * 256 + threadIdx.x; // 0..DM-1
    int row = blockIdx.y;                     // 0..M_-1
    const float* dr = dtmp + (size_t)row * DR;
    float acc = dt_b[n];
    #pragma unroll 8
    for (int k = 0; k < DR; k++) acc += dr[k] * dt_w[(size_t)k * DM + n];
    float sp = (acc > 20.f) ? acc : log1pf(__expf(acc));
    delta[(size_t)row * DM + n] = sp;
}

// ---------------------------------------------------------------------------
// Selective-scan. Block = 16 dm-channels x 16 ds-lanes. Sequential over L.
// Fused epilogue: ybar = (y_ssm + D*xc) * silu(res), stored bf16.
// ---------------------------------------------------------------------------
__global__ void scan_kernel(const float* __restrict__ delta, const float* __restrict__ xc,
                            const float* __restrict__ Bp, const float* __restrict__ Cp,
                            const float* __restrict__ res, const float* __restrict__ A_log,
                            const float* __restrict__ Dw, __bf16* __restrict__ ybar) {
    int blk = blockIdx.x;           // 0..255
    int b   = blk >> 7;             // /128
    int dm0 = (blk & 127) << 4;
    int t   = threadIdx.x;          // 256
    int grp = t >> 4, ds = t & 15;
    int dm  = dm0 + grp;

    float Aval = -__expf(A_log[dm * DS + ds]);
    float Dval = Dw[dm];

    size_t baseDM = (size_t)b * L_ * DM + dm;
    size_t baseDS = (size_t)b * L_ * DS + ds;

    float h = 0.f;
    // prefetch l = 0
    float dl = delta[baseDM], xv = xc[baseDM];
    float bv = Bp[baseDS],    cv = Cp[baseDS];

    for (int l = 0; l < L_; l++) {
        float dl2 = 0.f, xv2 = 0.f, bv2 = 0.f, cv2 = 0.f;
        if (l + 1 < L_) {
            size_t iDM = baseDM + (size_t)(l + 1) * DM;
            size_t iDS = baseDS + (size_t)(l + 1) * DS;
            dl2 = delta[iDM]; xv2 = xc[iDM];
            bv2 = Bp[iDS];    cv2 = Cp[iDS];
        }
        float dA = __expf(dl * Aval);
        h = fmaf(dA, h, dl * bv * xv);
        float y = h * cv;
        y += __shfl_xor(y, 1);
        y += __shfl_xor(y, 2);
        y += __shfl_xor(y, 4);
        y += __shfl_xor(y, 8);
        if (ds == 0) {
            size_t idx = baseDM + (size_t)l * DM;
            float rv = res[idx];
            float g = rv / (1.f + __expf(-rv));
            ybar[idx] = (__bf16)((y + Dval * xv) * g);
        }
        dl = dl2; xv = xv2; bv = bv2; cv = cv2;
    }
}

// ---------------------------------------------------------------------------
extern "C" void kernel_launch(void* const* d_in, const int* in_sizes, int n_in,
                              void* d_out, int out_size, void* d_ws, size_t ws_size,
                              hipStream_t stream) {
    // All reference tensors are float32.
    const float* x_in   = (const float*)d_in[0];   // (B,L,DIN)
    const float* W_in   = (const float*)d_in[1];   // (DIN,DM)
    const float* W_res  = (const float*)d_in[2];   // (DIN,DM)
    const float* W_out  = (const float*)d_in[3];   // (DM,DIN)
    const float* conv_w = (const float*)d_in[4];   // (DM,KC)
    const float* conv_b = (const float*)d_in[5];   // (DM)
    const float* A_log  = (const float*)d_in[6];   // (DM,DS)
    const float* Dw     = (const float*)d_in[7];   // (DM)
    const float* W_B    = (const float*)d_in[8];   // (DM,DS)
    const float* W_C    = (const float*)d_in[9];   // (DM,DS)
    const float* W_dt   = (const float*)d_in[10];  // (DM,DR)
    const float* dt_w   = (const float*)d_in[11];  // (DR,DM)
    const float* dt_b   = (const float*)d_in[12];  // (DM)

    // Workspace layout (f32 region then bf16 region)
    float* ws_f = (float*)d_ws;
    float* x     = ws_f;                        // M_*DM
    float* res   = x     + (size_t)M_ * DM;
    float* xc    = res   + (size_t)M_ * DM;
    float* delta = xc    + (size_t)M_ * DM;
    float* dtmp  = delta + (size_t)M_ * DM;     // M_*DR
    float* Bp    = dtmp  + (size_t)M_ * DR;     // M_*DS
    float* Cp    = Bp    + (size_t)M_ * DS;
    __bf16* bf_base = (__bf16*)(Cp + (size_t)M_ * DS);
    __bf16* ybar  = bf_base;                    // M_*DM
    __bf16* xinB  = ybar  + (size_t)M_ * DM;    // M_*DIN
    __bf16* WinT  = xinB  + (size_t)M_ * DIN;   // DM*DIN
    __bf16* WresT = WinT  + (size_t)DM * DIN;
    __bf16* WoutT = WresT + (size_t)DM * DIN;   // DIN*DM

    // bf16 operand prep
    convert_f32_bf16<<<(M_ * DIN) / 256, 256, 0, stream>>>(x_in, xinB, M_ * DIN);
    dim3 tb(32, 8);
    // W_in/W_res: (DIN,DM) -> (DM,DIN) bf16
    transpose_f32_bf16<<<dim3(DM / 32, DIN / 32), tb, 0, stream>>>(W_in,  WinT,  DIN, DM);
    transpose_f32_bf16<<<dim3(DM / 32, DIN / 32), tb, 0, stream>>>(W_res, WresT, DIN, DM);
    // W_out: (DM,DIN) -> (DIN,DM) bf16
    transpose_f32_bf16<<<dim3(DIN / 32, DM / 32), tb, 0, stream>>>(W_out, WoutT, DM, DIN);

    // x = x_in @ W_in ; res = x_in @ W_res   (M_ x DM, K=DIN)
    gemm_mfma<<<dim3(DM / 64, M_ / 64), 256, 0, stream>>>(xinB, WinT,  x,   M_, DM, DIN);
    gemm_mfma<<<dim3(DM / 64, M_ / 64), 256, 0, stream>>>(xinB, WresT, res, M_, DM, DIN);

    conv_silu<<<(M_ * DM) / 256, 256, 0, stream>>>(x, conv_w, conv_b, xc);

    proj_fused<<<M_, 256, 0, stream>>>(xc, W_B, W_C, W_dt, Bp, Cp, dtmp);

    delta_kernel<<<dim3(DM / 256, M_), 256, 0, stream>>>(dtmp, dt_w, dt_b, delta);

    scan_kernel<<<(B_ * DM) / 16, 256, 0, stream>>>(delta, xc, Bp, Cp, res, A_log, Dw, ybar);

    // out = ybar @ W_out  (M_ x DIN, K=DM), f32 output
    gemm_mfma<<<dim3(DIN / 64, M_ / 64), 256, 0, stream>>>(ybar, WoutT, (float*)d_out, M_, DIN, DM);
}

// Round 3
// 672.321 us; speedup vs baseline: 1.6793x; 1.6793x over previous
//
#include <hip/hip_runtime.h>
#include <hip/hip_bf16.h>

// Problem constants
constexpr int B_  = 2;
constexpr int L_  = 1024;
constexpr int DIN = 1024;
constexpr int DM  = 2048;
constexpr int DS  = 16;
constexpr int DR  = 128;
constexpr int KC  = 4;       // conv kernel size
constexpr int M_  = B_ * L_; // 2048 rows

// Chunked scan parameters
constexpr int NC = 32;               // number of chunks
constexpr int CL = L_ / NC;          // chunk length (32)
constexpr int S_ = B_ * DM * DS;     // 65536 scan states

typedef __bf16 bf16x8 __attribute__((ext_vector_type(8)));
typedef float  f32x4  __attribute__((ext_vector_type(4)));

// ---------------------------------------------------------------------------
// f32 -> bf16 elementwise convert (for MFMA A-operands)
// ---------------------------------------------------------------------------
__global__ void convert_f32_bf16(const float* __restrict__ in, __bf16* __restrict__ out, int n) {
    int i = blockIdx.x * 256 + threadIdx.x;
    if (i < n) out[i] = (__bf16)in[i];
}

// ---------------------------------------------------------------------------
// f32 transpose + bf16 convert: in (R x C) f32 -> out (C x R) bf16.
// ---------------------------------------------------------------------------
__global__ void transpose_f32_bf16(const float* __restrict__ in, __bf16* __restrict__ out,
                                   int R, int C) {
    __shared__ float tile[32][33];
    int bx = blockIdx.x * 32, by = blockIdx.y * 32;
    int tx = threadIdx.x, ty = threadIdx.y; // (32, 8)
    #pragma unroll
    for (int j = 0; j < 32; j += 8) {
        tile[ty + j][tx] = in[(size_t)(by + ty + j) * C + (bx + tx)];
    }
    __syncthreads();
    #pragma unroll
    for (int j = 0; j < 32; j += 8) {
        out[(size_t)(bx + ty + j) * R + (by + tx)] = (__bf16)tile[tx][ty + j];
    }
}

// ---------------------------------------------------------------------------
// MFMA bf16 GEMM: C(MxN) = A(MxK) @ B(KxN), BT = B^T (N x K) row-major.
// Wave = 32x32 via 2x2 mfma_f32_16x16x32_bf16; block = 4 waves = 64x64.
// ---------------------------------------------------------------------------
__global__ void gemm_mfma(const __bf16* __restrict__ A, const __bf16* __restrict__ BT,
                          float* __restrict__ Cout, int M, int N, int K) {
    int lane = threadIdx.x & 63;
    int wave = threadIdx.x >> 6;        // 0..3
    int wm = wave >> 1, wn = wave & 1;
    int m0 = blockIdx.y * 64 + wm * 32;
    int n0 = blockIdx.x * 64 + wn * 32;
    int quad = lane >> 4, r = lane & 15;

    f32x4 acc[2][2] = {};

    const __bf16* a0p = A  + (size_t)(m0 +      r) * K + quad * 8;
    const __bf16* a1p = A  + (size_t)(m0 + 16 + r) * K + quad * 8;
    const __bf16* b0p = BT + (size_t)(n0 +      r) * K + quad * 8;
    const __bf16* b1p = BT + (size_t)(n0 + 16 + r) * K + quad * 8;

    for (int k0 = 0; k0 < K; k0 += 32) {
        bf16x8 a0 = *(const bf16x8*)(a0p + k0);
        bf16x8 a1 = *(const bf16x8*)(a1p + k0);
        bf16x8 b0 = *(const bf16x8*)(b0p + k0);
        bf16x8 b1 = *(const bf16x8*)(b1p + k0);
        acc[0][0] = __builtin_amdgcn_mfma_f32_16x16x32_bf16(a0, b0, acc[0][0], 0, 0, 0);
        acc[0][1] = __builtin_amdgcn_mfma_f32_16x16x32_bf16(a0, b1, acc[0][1], 0, 0, 0);
        acc[1][0] = __builtin_amdgcn_mfma_f32_16x16x32_bf16(a1, b0, acc[1][0], 0, 0, 0);
        acc[1][1] = __builtin_amdgcn_mfma_f32_16x16x32_bf16(a1, b1, acc[1][1], 0, 0, 0);
    }

    #pragma unroll
    for (int im = 0; im < 2; im++) {
        #pragma unroll
        for (int in_ = 0; in_ < 2; in_++) {
            int col = n0 + in_ * 16 + r;
            #pragma unroll
            for (int j = 0; j < 4; j++) {
                int row = m0 + im * 16 + quad * 4 + j;
                Cout[(size_t)row * N + col] = acc[im][in_][j];
            }
        }
    }
}

// ---------------------------------------------------------------------------
// Causal depthwise conv (K=4) + bias + SiLU. x (B,L,DM) f32 -> xc f32.
// ---------------------------------------------------------------------------
__global__ void conv_silu(const float* __restrict__ x, const float* __restrict__ w,
                          const float* __restrict__ bias, float* __restrict__ xc) {
    int idx = blockIdx.x * 256 + threadIdx.x;     // 0 .. B*L*DM
    int d  = idx % DM;
    int bl = idx / DM;
    int l  = bl % L_;
    float acc = bias[d];
    #pragma unroll
    for (int i = 0; i < KC; i++) {
        int li = l - (KC - 1) + i;
        if (li >= 0) acc += x[idx + (i - (KC - 1)) * DM] * w[d * KC + i];
    }
    xc[idx] = acc / (1.f + __expf(-acc));
}

// ---------------------------------------------------------------------------
// Fused projections: Bp = xc@W_B, Cp = xc@W_C, dtmp = xc@W_dt.
// ---------------------------------------------------------------------------
__global__ void proj_fused(const float* __restrict__ xc,
                           const float* __restrict__ W_B, const float* __restrict__ W_C,
                           const float* __restrict__ W_dt,
                           float* __restrict__ Bp, float* __restrict__ Cp,
                           float* __restrict__ dtmp) {
    int row = blockIdx.x;   // 0..M_-1
    int t = threadIdx.x;    // 256
    __shared__ float sx[256];

    const float* Wp; int ldw, col;
    if (t < 16)       { Wp = W_B;  ldw = DS; col = t; }
    else if (t < 32)  { Wp = W_C;  ldw = DS; col = t - 16; }
    else if (t < 160) { Wp = W_dt; ldw = DR; col = t - 32; }
    else              { Wp = W_B;  ldw = 0;  col = 0; }

    const float* xr = xc + (size_t)row * DM;
    float acc = 0.f;
    for (int c0 = 0; c0 < DM; c0 += 256) {
        sx[t] = xr[c0 + t];
        __syncthreads();
        #pragma unroll 8
        for (int j = 0; j < 256; j++) {
            acc += sx[j] * Wp[(size_t)(c0 + j) * ldw + col];
        }
        __syncthreads();
    }
    if (t < 16)       Bp[(size_t)row * DS + t]          = acc;
    else if (t < 32)  Cp[(size_t)row * DS + (t - 16)]   = acc;
    else if (t < 160) dtmp[(size_t)row * DR + (t - 32)] = acc;
}

// ---------------------------------------------------------------------------
// delta = softplus(dtmp @ dt_w + dt_b). dtmp (M,DR), dt_w (DR,DM), all f32.
// ---------------------------------------------------------------------------
__global__ void delta_kernel(const float* __restrict__ dtmp, const float* __restrict__ dt_w,
                             const float* __restrict__ dt_b, float* __restrict__ delta) {
    int n   = blockIdx.x * 256 + threadIdx.x; // 0..DM-1
    int row = blockIdx.y;                     // 0..M_-1
    const float* dr = dtmp + (size_t)row * DR;
    float acc = dt_b[n];
    #pragma unroll 8
    for (int k = 0; k < DR; k++) acc += dr[k] * dt_w[(size_t)k * DM + n];
    float sp = (acc > 20.f) ? acc : log1pf(__expf(acc));
    delta[(size_t)row * DM + n] = sp;
}

// ---------------------------------------------------------------------------
// Chunked scan, phase 1: per (b, dm-tile, chunk) block, compute per-state
// chunk-local (prod dA, final h) with h_in = 0.
// Block = 256 threads = 16 dm x 16 ds. Grid = B * (DM/16) * NC.
// Summary layout: [c][s] where s = (b*DM + dm)*DS + ds (coalesced everywhere).
// ---------------------------------------------------------------------------
__global__ void scan_phase1(const float* __restrict__ delta, const float* __restrict__ xc,
                            const float* __restrict__ Bp, const float* __restrict__ A_log,
                            float* __restrict__ aprod, float* __restrict__ cend) {
    int blk = blockIdx.x;
    int c   = blk % NC;
    int rem = blk / NC;
    int dmt = rem % (DM / 16);
    int b   = rem / (DM / 16);
    int t   = threadIdx.x;
    int grp = t >> 4, ds = t & 15;
    int dm  = dmt * 16 + grp;

    float Aval = -__expf(A_log[dm * DS + ds]);

    int l0 = c * CL;
    size_t baseDM = (size_t)b * L_ * DM + (size_t)l0 * DM + dm;
    size_t baseDS = (size_t)b * L_ * DS + (size_t)l0 * DS + ds;

    float h = 0.f, ap = 1.f;
    float dl = delta[baseDM], xv = xc[baseDM], bv = Bp[baseDS];
    for (int j = 0; j < CL; j++) {
        float dl2 = 0.f, xv2 = 0.f, bv2 = 0.f;
        if (j + 1 < CL) {
            dl2 = delta[baseDM + (size_t)(j + 1) * DM];
            xv2 = xc[baseDM + (size_t)(j + 1) * DM];
            bv2 = Bp[baseDS + (size_t)(j + 1) * DS];
        }
        float dA = __expf(dl * Aval);
        ap *= dA;
        h = fmaf(dA, h, dl * bv * xv);
        dl = dl2; xv = xv2; bv = bv2;
    }
    size_t s = (size_t)(b * DM + dm) * DS + ds;
    aprod[(size_t)c * S_ + s] = ap;
    cend[(size_t)c * S_ + s]  = h;
}

// ---------------------------------------------------------------------------
// Chunked scan, phase 2: scan the NC chunk summaries per state, emitting the
// initial h for each chunk. 65536 threads, fully coalesced, unrolled.
// ---------------------------------------------------------------------------
__global__ void scan_phase2(const float* __restrict__ aprod, const float* __restrict__ cend,
                            float* __restrict__ hinit) {
    int u = blockIdx.x * 256 + threadIdx.x;   // 0..S_-1
    float h = 0.f;
    #pragma unroll
    for (int c = 0; c < NC; c++) {
        hinit[(size_t)c * S_ + u] = h;
        h = fmaf(aprod[(size_t)c * S_ + u], h, cend[(size_t)c * S_ + u]);
    }
}

// ---------------------------------------------------------------------------
// Chunked scan, phase 3: replay each chunk from its exact h_init, computing
// y = C·h, then fused epilogue ybar = (y + D*xc) * silu(res) -> bf16.
// ---------------------------------------------------------------------------
__global__ void scan_phase3(const float* __restrict__ delta, const float* __restrict__ xc,
                            const float* __restrict__ Bp, const float* __restrict__ Cp,
                            const float* __restrict__ res, const float* __restrict__ A_log,
                            const float* __restrict__ Dw, const float* __restrict__ hinit,
                            __bf16* __restrict__ ybar) {
    int blk = blockIdx.x;
    int c   = blk % NC;
    int rem = blk / NC;
    int dmt = rem % (DM / 16);
    int b   = rem / (DM / 16);
    int t   = threadIdx.x;
    int grp = t >> 4, ds = t & 15;
    int dm  = dmt * 16 + grp;

    float Aval = -__expf(A_log[dm * DS + ds]);
    float Dval = Dw[dm];

    int l0 = c * CL;
    size_t baseDM = (size_t)b * L_ * DM + (size_t)l0 * DM + dm;
    size_t baseDS = (size_t)b * L_ * DS + (size_t)l0 * DS + ds;
    size_t s = (size_t)(b * DM + dm) * DS + ds;

    float h = hinit[(size_t)c * S_ + s];
    float dl = delta[baseDM], xv = xc[baseDM];
    float bv = Bp[baseDS],    cv = Cp[baseDS];

    for (int j = 0; j < CL; j++) {
        float dl2 = 0.f, xv2 = 0.f, bv2 = 0.f, cv2 = 0.f;
        if (j + 1 < CL) {
            dl2 = delta[baseDM + (size_t)(j + 1) * DM];
            xv2 = xc[baseDM + (size_t)(j + 1) * DM];
            bv2 = Bp[baseDS + (size_t)(j + 1) * DS];
            cv2 = Cp[baseDS + (size_t)(j + 1) * DS];
        }
        float dA = __expf(dl * Aval);
        h = fmaf(dA, h, dl * bv * xv);
        float y = h * cv;
        y += __shfl_xor(y, 1);
        y += __shfl_xor(y, 2);
        y += __shfl_xor(y, 4);
        y += __shfl_xor(y, 8);
        if (ds == 0) {
            size_t idx = baseDM + (size_t)j * DM;
            float rv = res[idx];
            float g = rv / (1.f + __expf(-rv));
            ybar[idx] = (__bf16)((y + Dval * xv) * g);
        }
        dl = dl2; xv = xv2; bv = bv2; cv = cv2;
    }
}

// ---------------------------------------------------------------------------
extern "C" void kernel_launch(void* const* d_in, const int* in_sizes, int n_in,
                              void* d_out, int out_size, void* d_ws, size_t ws_size,
                              hipStream_t stream) {
    // All reference tensors are float32.
    const float* x_in   = (const float*)d_in[0];
    const float* W_in   = (const float*)d_in[1];
    const float* W_res  = (const float*)d_in[2];
    const float* W_out  = (const float*)d_in[3];
    const float* conv_w = (const float*)d_in[4];
    const float* conv_b = (const float*)d_in[5];
    const float* A_log  = (const float*)d_in[6];
    const float* Dw     = (const float*)d_in[7];
    const float* W_B    = (const float*)d_in[8];
    const float* W_C    = (const float*)d_in[9];
    const float* W_dt   = (const float*)d_in[10];
    const float* dt_w   = (const float*)d_in[11];
    const float* dt_b   = (const float*)d_in[12];

    // Workspace layout (f32 region then bf16 region)
    float* ws_f = (float*)d_ws;
    float* x     = ws_f;                        // M_*DM (dead after conv -> reused by scan summaries)
    float* res   = x     + (size_t)M_ * DM;
    float* xc    = res   + (size_t)M_ * DM;
    float* delta = xc    + (size_t)M_ * DM;
    float* dtmp  = delta + (size_t)M_ * DM;     // M_*DR
    float* Bp    = dtmp  + (size_t)M_ * DR;     // M_*DS
    float* Cp    = Bp    + (size_t)M_ * DS;
    __bf16* bf_base = (__bf16*)(Cp + (size_t)M_ * DS);
    __bf16* ybar  = bf_base;                    // M_*DM
    __bf16* xinB  = ybar  + (size_t)M_ * DM;    // M_*DIN
    __bf16* WinT  = xinB  + (size_t)M_ * DIN;   // DM*DIN
    __bf16* WresT = WinT  + (size_t)DM * DIN;
    __bf16* WoutT = WresT + (size_t)DM * DIN;   // DIN*DM
    // Scan summaries: aprod/cend overlay the dead x buffer (2 * NC*S_ = M_*DM floats exactly)
    float* aprod = x;                           // NC*S_
    float* cend  = x + (size_t)NC * S_;         // NC*S_
    float* hinit = (float*)(WoutT + (size_t)DIN * DM); // NC*S_ (new, 8 MB)

    // bf16 operand prep
    convert_f32_bf16<<<(M_ * DIN) / 256, 256, 0, stream>>>(x_in, xinB, M_ * DIN);
    dim3 tb(32, 8);
    transpose_f32_bf16<<<dim3(DM / 32, DIN / 32), tb, 0, stream>>>(W_in,  WinT,  DIN, DM);
    transpose_f32_bf16<<<dim3(DM / 32, DIN / 32), tb, 0, stream>>>(W_res, WresT, DIN, DM);
    transpose_f32_bf16<<<dim3(DIN / 32, DM / 32), tb, 0, stream>>>(W_out, WoutT, DM, DIN);

    // x = x_in @ W_in ; res = x_in @ W_res   (M_ x DM, K=DIN)
    gemm_mfma<<<dim3(DM / 64, M_ / 64), 256, 0, stream>>>(xinB, WinT,  x,   M_, DM, DIN);
    gemm_mfma<<<dim3(DM / 64, M_ / 64), 256, 0, stream>>>(xinB, WresT, res, M_, DM, DIN);

    conv_silu<<<(M_ * DM) / 256, 256, 0, stream>>>(x, conv_w, conv_b, xc);

    proj_fused<<<M_, 256, 0, stream>>>(xc, W_B, W_C, W_dt, Bp, Cp, dtmp);

    delta_kernel<<<dim3(DM / 256, M_), 256, 0, stream>>>(dtmp, dt_w, dt_b, delta);

    // Chunked selective scan (x buffer is dead here; aprod/cend overlay it)
    int nblk = B_ * (DM / 16) * NC;   // 8192
    scan_phase1<<<nblk, 256, 0, stream>>>(delta, xc, Bp, A_log, aprod, cend);
    scan_phase2<<<S_ / 256, 256, 0, stream>>>(aprod, cend, hinit);
    scan_phase3<<<nblk, 256, 0, stream>>>(delta, xc, Bp, Cp, res, A_log, Dw, hinit, ybar);

    // out = ybar @ W_out  (M_ x DIN, K=DM), f32 output
    gemm_mfma<<<dim3(DIN / 64, M_ / 64), 256, 0, stream>>>(ybar, WoutT, (float*)d_out, M_, DIN, DM);
}

// Round 4
// 520.187 us; speedup vs baseline: 2.1704x; 1.2925x over previous
//
#include <hip/hip_runtime.h>
#include <hip/hip_bf16.h>

// Problem constants
constexpr int B_  = 2;
constexpr int L_  = 1024;
constexpr int DIN = 1024;
constexpr int DM  = 2048;
constexpr int DS  = 16;
constexpr int DR  = 128;
constexpr int KC  = 4;       // conv kernel size
constexpr int M_  = B_ * L_; // 2048 rows
constexpr int NP  = 192;     // packed projection width (16+16+128 padded to 192)

// Chunked scan parameters
constexpr int NC = 32;               // number of chunks
constexpr int CL = L_ / NC;          // chunk length (32)
constexpr int S_ = B_ * DM * DS;     // 65536 scan states

typedef __bf16 bf16x8 __attribute__((ext_vector_type(8)));
typedef float  f32x4  __attribute__((ext_vector_type(4)));

// ---------------------------------------------------------------------------
// f32 -> bf16 elementwise convert
// ---------------------------------------------------------------------------
__global__ void convert_f32_bf16(const float* __restrict__ in, __bf16* __restrict__ out, int n) {
    int i = blockIdx.x * 256 + threadIdx.x;
    if (i < n) out[i] = (__bf16)in[i];
}

// ---------------------------------------------------------------------------
// f32 transpose + bf16 convert: in (R x C) f32 -> out (C x R) bf16.
// ---------------------------------------------------------------------------
__global__ void transpose_f32_bf16(const float* __restrict__ in, __bf16* __restrict__ out,
                                   int R, int C) {
    __shared__ float tile[32][33];
    int bx = blockIdx.x * 32, by = blockIdx.y * 32;
    int tx = threadIdx.x, ty = threadIdx.y; // (32, 8)
    #pragma unroll
    for (int j = 0; j < 32; j += 8) {
        tile[ty + j][tx] = in[(size_t)(by + ty + j) * C + (bx + tx)];
    }
    __syncthreads();
    #pragma unroll
    for (int j = 0; j < 32; j += 8) {
        out[(size_t)(bx + ty + j) * R + (by + tx)] = (__bf16)tile[tx][ty + j];
    }
}

// ---------------------------------------------------------------------------
// Pack [W_B | W_C | W_dt | 0] into BT form: out (NP x DM) bf16,
// out[n][k] = W[k][n'] for the matching source.
// ---------------------------------------------------------------------------
__global__ void pack_projw(const float* __restrict__ W_B, const float* __restrict__ W_C,
                           const float* __restrict__ W_dt, __bf16* __restrict__ out) {
    int i = blockIdx.x * 256 + threadIdx.x;   // 0 .. NP*DM
    int k = i % DM;
    int n = i / DM;
    float v = 0.f;
    if (n < 16)        v = W_B[(size_t)k * DS + n];
    else if (n < 32)   v = W_C[(size_t)k * DS + (n - 16)];
    else if (n < 160)  v = W_dt[(size_t)k * DR + (n - 32)];
    out[i] = (__bf16)v;
}

// ---------------------------------------------------------------------------
// Split packed projection output P (M x NP f32) -> Bp, Cp (f32), dtmp (bf16).
// ---------------------------------------------------------------------------
__global__ void split_proj(const float* __restrict__ P, float* __restrict__ Bp,
                           float* __restrict__ Cp, __bf16* __restrict__ dtmpB) {
    int i = blockIdx.x * 256 + threadIdx.x;   // 0 .. M_*160
    int row = i / 160, c = i % 160;
    float v = P[(size_t)row * NP + c];
    if (c < 16)       Bp[(size_t)row * DS + c] = v;
    else if (c < 32)  Cp[(size_t)row * DS + (c - 16)] = v;
    else              dtmpB[(size_t)row * DR + (c - 32)] = (__bf16)v;
}

// ---------------------------------------------------------------------------
// MFMA bf16 GEMM: C(MxN) = A(MxK) @ B(KxN), BT = B^T (N x K) row-major.
// Wave = 32x32 via 2x2 mfma_f32_16x16x32_bf16; block = 4 waves = 64x64.
// ---------------------------------------------------------------------------
__global__ void gemm_mfma(const __bf16* __restrict__ A, const __bf16* __restrict__ BT,
                          float* __restrict__ Cout, int M, int N, int K) {
    int lane = threadIdx.x & 63;
    int wave = threadIdx.x >> 6;        // 0..3
    int wm = wave >> 1, wn = wave & 1;
    int m0 = blockIdx.y * 64 + wm * 32;
    int n0 = blockIdx.x * 64 + wn * 32;
    int quad = lane >> 4, r = lane & 15;

    f32x4 acc[2][2] = {};

    const __bf16* a0p = A  + (size_t)(m0 +      r) * K + quad * 8;
    const __bf16* a1p = A  + (size_t)(m0 + 16 + r) * K + quad * 8;
    const __bf16* b0p = BT + (size_t)(n0 +      r) * K + quad * 8;
    const __bf16* b1p = BT + (size_t)(n0 + 16 + r) * K + quad * 8;

    for (int k0 = 0; k0 < K; k0 += 32) {
        bf16x8 a0 = *(const bf16x8*)(a0p + k0);
        bf16x8 a1 = *(const bf16x8*)(a1p + k0);
        bf16x8 b0 = *(const bf16x8*)(b0p + k0);
        bf16x8 b1 = *(const bf16x8*)(b1p + k0);
        acc[0][0] = __builtin_amdgcn_mfma_f32_16x16x32_bf16(a0, b0, acc[0][0], 0, 0, 0);
        acc[0][1] = __builtin_amdgcn_mfma_f32_16x16x32_bf16(a0, b1, acc[0][1], 0, 0, 0);
        acc[1][0] = __builtin_amdgcn_mfma_f32_16x16x32_bf16(a1, b0, acc[1][0], 0, 0, 0);
        acc[1][1] = __builtin_amdgcn_mfma_f32_16x16x32_bf16(a1, b1, acc[1][1], 0, 0, 0);
    }

    #pragma unroll
    for (int im = 0; im < 2; im++) {
        #pragma unroll
        for (int in_ = 0; in_ < 2; in_++) {
            int col = n0 + in_ * 16 + r;
            #pragma unroll
            for (int j = 0; j < 4; j++) {
                int row = m0 + im * 16 + quad * 4 + j;
                Cout[(size_t)row * N + col] = acc[im][in_][j];
            }
        }
    }
}

// ---------------------------------------------------------------------------
// MFMA GEMM + bias + softplus epilogue: delta = softplus(A@B + bias[col]).
// ---------------------------------------------------------------------------
__global__ void gemm_mfma_softplus(const __bf16* __restrict__ A, const __bf16* __restrict__ BT,
                                   const float* __restrict__ bias, float* __restrict__ Cout,
                                   int M, int N, int K) {
    int lane = threadIdx.x & 63;
    int wave = threadIdx.x >> 6;
    int wm = wave >> 1, wn = wave & 1;
    int m0 = blockIdx.y * 64 + wm * 32;
    int n0 = blockIdx.x * 64 + wn * 32;
    int quad = lane >> 4, r = lane & 15;

    f32x4 acc[2][2] = {};

    const __bf16* a0p = A  + (size_t)(m0 +      r) * K + quad * 8;
    const __bf16* a1p = A  + (size_t)(m0 + 16 + r) * K + quad * 8;
    const __bf16* b0p = BT + (size_t)(n0 +      r) * K + quad * 8;
    const __bf16* b1p = BT + (size_t)(n0 + 16 + r) * K + quad * 8;

    for (int k0 = 0; k0 < K; k0 += 32) {
        bf16x8 a0 = *(const bf16x8*)(a0p + k0);
        bf16x8 a1 = *(const bf16x8*)(a1p + k0);
        bf16x8 b0 = *(const bf16x8*)(b0p + k0);
        bf16x8 b1 = *(const bf16x8*)(b1p + k0);
        acc[0][0] = __builtin_amdgcn_mfma_f32_16x16x32_bf16(a0, b0, acc[0][0], 0, 0, 0);
        acc[0][1] = __builtin_amdgcn_mfma_f32_16x16x32_bf16(a0, b1, acc[0][1], 0, 0, 0);
        acc[1][0] = __builtin_amdgcn_mfma_f32_16x16x32_bf16(a1, b0, acc[1][0], 0, 0, 0);
        acc[1][1] = __builtin_amdgcn_mfma_f32_16x16x32_bf16(a1, b1, acc[1][1], 0, 0, 0);
    }

    #pragma unroll
    for (int im = 0; im < 2; im++) {
        #pragma unroll
        for (int in_ = 0; in_ < 2; in_++) {
            int col = n0 + in_ * 16 + r;
            float bz = bias[col];
            #pragma unroll
            for (int j = 0; j < 4; j++) {
                int row = m0 + im * 16 + quad * 4 + j;
                float v = acc[im][in_][j] + bz;
                float sp = (v > 20.f) ? v : log1pf(__expf(v));
                Cout[(size_t)row * N + col] = sp;
            }
        }
    }
}

// ---------------------------------------------------------------------------
// Causal depthwise conv (K=4) + bias + SiLU. Emits xc f32 AND xc bf16.
// ---------------------------------------------------------------------------
__global__ void conv_silu(const float* __restrict__ x, const float* __restrict__ w,
                          const float* __restrict__ bias, float* __restrict__ xc,
                          __bf16* __restrict__ xcB) {
    int idx = blockIdx.x * 256 + threadIdx.x;     // 0 .. B*L*DM
    int d  = idx % DM;
    int bl = idx / DM;
    int l  = bl % L_;
    float acc = bias[d];
    #pragma unroll
    for (int i = 0; i < KC; i++) {
        int li = l - (KC - 1) + i;
        if (li >= 0) acc += x[idx + (i - (KC - 1)) * DM] * w[d * KC + i];
    }
    float v = acc / (1.f + __expf(-acc));
    xc[idx] = v;
    xcB[idx] = (__bf16)v;
}

// ---------------------------------------------------------------------------
// Chunked scan, phase 1: per-chunk (prod dA, final h) with h_in = 0.
// ---------------------------------------------------------------------------
__global__ void scan_phase1(const float* __restrict__ delta, const float* __restrict__ xc,
                            const float* __restrict__ Bp, const float* __restrict__ A_log,
                            float* __restrict__ aprod, float* __restrict__ cend) {
    int blk = blockIdx.x;
    int c   = blk % NC;
    int rem = blk / NC;
    int dmt = rem % (DM / 16);
    int b   = rem / (DM / 16);
    int t   = threadIdx.x;
    int grp = t >> 4, ds = t & 15;
    int dm  = dmt * 16 + grp;

    float Aval = -__expf(A_log[dm * DS + ds]);

    int l0 = c * CL;
    size_t baseDM = (size_t)b * L_ * DM + (size_t)l0 * DM + dm;
    size_t baseDS = (size_t)b * L_ * DS + (size_t)l0 * DS + ds;

    float h = 0.f, ap = 1.f;
    float dl = delta[baseDM], xv = xc[baseDM], bv = Bp[baseDS];
    for (int j = 0; j < CL; j++) {
        float dl2 = 0.f, xv2 = 0.f, bv2 = 0.f;
        if (j + 1 < CL) {
            dl2 = delta[baseDM + (size_t)(j + 1) * DM];
            xv2 = xc[baseDM + (size_t)(j + 1) * DM];
            bv2 = Bp[baseDS + (size_t)(j + 1) * DS];
        }
        float dA = __expf(dl * Aval);
        ap *= dA;
        h = fmaf(dA, h, dl * bv * xv);
        dl = dl2; xv = xv2; bv = bv2;
    }
    size_t s = (size_t)(b * DM + dm) * DS + ds;
    aprod[(size_t)c * S_ + s] = ap;
    cend[(size_t)c * S_ + s]  = h;
}

// ---------------------------------------------------------------------------
// Chunked scan, phase 2: scan chunk summaries, emit h_init per chunk.
// ---------------------------------------------------------------------------
__global__ void scan_phase2(const float* __restrict__ aprod, const float* __restrict__ cend,
                            float* __restrict__ hinit) {
    int u = blockIdx.x * 256 + threadIdx.x;   // 0..S_-1
    float h = 0.f;
    #pragma unroll
    for (int c = 0; c < NC; c++) {
        hinit[(size_t)c * S_ + u] = h;
        h = fmaf(aprod[(size_t)c * S_ + u], h, cend[(size_t)c * S_ + u]);
    }
}

// ---------------------------------------------------------------------------
// Chunked scan, phase 3: replay from exact h_init, y = C·h, fused epilogue
// ybar = (y + D*xc) * silu(res) -> bf16.
// ---------------------------------------------------------------------------
__global__ void scan_phase3(const float* __restrict__ delta, const float* __restrict__ xc,
                            const float* __restrict__ Bp, const float* __restrict__ Cp,
                            const float* __restrict__ res, const float* __restrict__ A_log,
                            const float* __restrict__ Dw, const float* __restrict__ hinit,
                            __bf16* __restrict__ ybar) {
    int blk = blockIdx.x;
    int c   = blk % NC;
    int rem = blk / NC;
    int dmt = rem % (DM / 16);
    int b   = rem / (DM / 16);
    int t   = threadIdx.x;
    int grp = t >> 4, ds = t & 15;
    int dm  = dmt * 16 + grp;

    float Aval = -__expf(A_log[dm * DS + ds]);
    float Dval = Dw[dm];

    int l0 = c * CL;
    size_t baseDM = (size_t)b * L_ * DM + (size_t)l0 * DM + dm;
    size_t baseDS = (size_t)b * L_ * DS + (size_t)l0 * DS + ds;
    size_t s = (size_t)(b * DM + dm) * DS + ds;

    float h = hinit[(size_t)c * S_ + s];
    float dl = delta[baseDM], xv = xc[baseDM];
    float bv = Bp[baseDS],    cv = Cp[baseDS];

    for (int j = 0; j < CL; j++) {
        float dl2 = 0.f, xv2 = 0.f, bv2 = 0.f, cv2 = 0.f;
        if (j + 1 < CL) {
            dl2 = delta[baseDM + (size_t)(j + 1) * DM];
            xv2 = xc[baseDM + (size_t)(j + 1) * DM];
            bv2 = Bp[baseDS + (size_t)(j + 1) * DS];
            cv2 = Cp[baseDS + (size_t)(j + 1) * DS];
        }
        float dA = __expf(dl * Aval);
        h = fmaf(dA, h, dl * bv * xv);
        float y = h * cv;
        y += __shfl_xor(y, 1);
        y += __shfl_xor(y, 2);
        y += __shfl_xor(y, 4);
        y += __shfl_xor(y, 8);
        if (ds == 0) {
            size_t idx = baseDM + (size_t)j * DM;
            float rv = res[idx];
            float g = rv / (1.f + __expf(-rv));
            ybar[idx] = (__bf16)((y + Dval * xv) * g);
        }
        dl = dl2; xv = xv2; bv = bv2; cv = cv2;
    }
}

// ---------------------------------------------------------------------------
extern "C" void kernel_launch(void* const* d_in, const int* in_sizes, int n_in,
                              void* d_out, int out_size, void* d_ws, size_t ws_size,
                              hipStream_t stream) {
    // All reference tensors are float32.
    const float* x_in   = (const float*)d_in[0];
    const float* W_in   = (const float*)d_in[1];
    const float* W_res  = (const float*)d_in[2];
    const float* W_out  = (const float*)d_in[3];
    const float* conv_w = (const float*)d_in[4];
    const float* conv_b = (const float*)d_in[5];
    const float* A_log  = (const float*)d_in[6];
    const float* Dw     = (const float*)d_in[7];
    const float* W_B    = (const float*)d_in[8];
    const float* W_C    = (const float*)d_in[9];
    const float* W_dt   = (const float*)d_in[10];
    const float* dt_w   = (const float*)d_in[11];
    const float* dt_b   = (const float*)d_in[12];

    // ---------------- Workspace layout ----------------
    float* ws_f = (float*)d_ws;
    float* x     = ws_f;                        // M_*DM (dead after conv -> aprod/cend overlay)
    float* res   = x     + (size_t)M_ * DM;
    float* xc    = res   + (size_t)M_ * DM;
    float* delta = xc    + (size_t)M_ * DM;
    float* P     = delta + (size_t)M_ * DM;     // M_*NP packed projections
    float* Bp    = P     + (size_t)M_ * NP;     // M_*DS
    float* Cp    = Bp    + (size_t)M_ * DS;
    __bf16* bf_base = (__bf16*)(Cp + (size_t)M_ * DS);
    __bf16* ybar  = bf_base;                    // M_*DM
    __bf16* xinB  = ybar  + (size_t)M_ * DM;    // M_*DIN (dead after input GEMMs)
    __bf16* WinT  = xinB  + (size_t)M_ * DIN;   // DM*DIN (dead after input GEMMs)
    __bf16* WresT = WinT  + (size_t)DM * DIN;   // DM*DIN (dead after input GEMMs)
    __bf16* WoutT = WresT + (size_t)DM * DIN;   // DIN*DM (live to the end)
    __bf16* xcB   = WoutT + (size_t)DIN * DM;   // M_*DM
    __bf16* projW = xcB   + (size_t)M_ * DM;    // NP*DM
    __bf16* dtwT  = projW + (size_t)NP * DM;    // DM*DR
    __bf16* dtmpB = dtwT  + (size_t)DM * DR;    // M_*DR
    // Scan summaries overlay dead buffers:
    float* aprod = x;                           // NC*S_ (overlay x: exactly M_*DM floats for both)
    float* cend  = x + (size_t)NC * S_;
    float* hinit = (float*)xinB;                // NC*S_ f32 = 8 MB overlays xinB+WinT (dead by then)

    // ---------------- bf16 operand prep ----------------
    convert_f32_bf16<<<(M_ * DIN) / 256, 256, 0, stream>>>(x_in, xinB, M_ * DIN);
    dim3 tb(32, 8);
    transpose_f32_bf16<<<dim3(DM / 32, DIN / 32), tb, 0, stream>>>(W_in,  WinT,  DIN, DM);
    transpose_f32_bf16<<<dim3(DM / 32, DIN / 32), tb, 0, stream>>>(W_res, WresT, DIN, DM);
    transpose_f32_bf16<<<dim3(DIN / 32, DM / 32), tb, 0, stream>>>(W_out, WoutT, DM, DIN);
    transpose_f32_bf16<<<dim3(DM / 32, DR / 32),  tb, 0, stream>>>(dt_w,  dtwT,  DR, DM);
    pack_projw<<<(NP * DM) / 256, 256, 0, stream>>>(W_B, W_C, W_dt, projW);

    // x = x_in @ W_in ; res = x_in @ W_res   (M_ x DM, K=DIN)
    gemm_mfma<<<dim3(DM / 64, M_ / 64), 256, 0, stream>>>(xinB, WinT,  x,   M_, DM, DIN);
    gemm_mfma<<<dim3(DM / 64, M_ / 64), 256, 0, stream>>>(xinB, WresT, res, M_, DM, DIN);

    conv_silu<<<(M_ * DM) / 256, 256, 0, stream>>>(x, conv_w, conv_b, xc, xcB);

    // Packed projections: P = xc @ [W_B|W_C|W_dt]  (M_ x NP, K=DM)
    gemm_mfma<<<dim3(NP / 64, M_ / 64), 256, 0, stream>>>(xcB, projW, P, M_, NP, DM);
    split_proj<<<(M_ * 160) / 256, 256, 0, stream>>>(P, Bp, Cp, dtmpB);

    // delta = softplus(dtmp @ dt_w + dt_b)  (M_ x DM, K=DR)
    gemm_mfma_softplus<<<dim3(DM / 64, M_ / 64), 256, 0, stream>>>(dtmpB, dtwT, dt_b, delta, M_, DM, DR);

    // Chunked selective scan
    int nblk = B_ * (DM / 16) * NC;   // 8192
    scan_phase1<<<nblk, 256, 0, stream>>>(delta, xc, Bp, A_log, aprod, cend);
    scan_phase2<<<S_ / 256, 256, 0, stream>>>(aprod, cend, hinit);
    scan_phase3<<<nblk, 256, 0, stream>>>(delta, xc, Bp, Cp, res, A_log, Dw, hinit, ybar);

    // out = ybar @ W_out  (M_ x DIN, K=DM), f32 output
    gemm_mfma<<<dim3(DIN / 64, M_ / 64), 256, 0, stream>>>(ybar, WoutT, (float*)d_out, M_, DIN, DM);
}

// Round 5
// 448.064 us; speedup vs baseline: 2.5197x; 1.1610x over previous
//
#include <hip/hip_runtime.h>
#include <hip/hip_bf16.h>

// Problem constants
constexpr int B_  = 2;
constexpr int L_  = 1024;
constexpr int DIN = 1024;
constexpr int DM  = 2048;
constexpr int DS  = 16;
constexpr int DR  = 128;
constexpr int KC  = 4;       // conv kernel size
constexpr int M_  = B_ * L_; // 2048 rows
constexpr int NP  = 192;     // packed projection width (16+16+128 padded to 192)

// Chunked scan parameters
constexpr int NC = 64;               // number of chunks
constexpr int CL = L_ / NC;          // chunk length (16)
constexpr int S_ = B_ * DM * DS;     // 65536 scan states

typedef __bf16 bf16x8 __attribute__((ext_vector_type(8)));
typedef float  f32x4  __attribute__((ext_vector_type(4)));

// ---------------------------------------------------------------------------
// f32 -> bf16 elementwise convert
// ---------------------------------------------------------------------------
__global__ void convert_f32_bf16(const float* __restrict__ in, __bf16* __restrict__ out, int n) {
    int i = blockIdx.x * 256 + threadIdx.x;
    if (i < n) out[i] = (__bf16)in[i];
}

// ---------------------------------------------------------------------------
// f32 transpose + bf16 convert: in (R x C) f32 -> out (C x R) bf16.
// ---------------------------------------------------------------------------
__global__ void transpose_f32_bf16(const float* __restrict__ in, __bf16* __restrict__ out,
                                   int R, int C) {
    __shared__ float tile[32][33];
    int bx = blockIdx.x * 32, by = blockIdx.y * 32;
    int tx = threadIdx.x, ty = threadIdx.y; // (32, 8)
    #pragma unroll
    for (int j = 0; j < 32; j += 8) {
        tile[ty + j][tx] = in[(size_t)(by + ty + j) * C + (bx + tx)];
    }
    __syncthreads();
    #pragma unroll
    for (int j = 0; j < 32; j += 8) {
        out[(size_t)(bx + ty + j) * R + (by + tx)] = (__bf16)tile[tx][ty + j];
    }
}

// ---------------------------------------------------------------------------
// Pack [W_B | W_C | W_dt | 0] into BT form: out (NP x DM) bf16.
// ---------------------------------------------------------------------------
__global__ void pack_projw(const float* __restrict__ W_B, const float* __restrict__ W_C,
                           const float* __restrict__ W_dt, __bf16* __restrict__ out) {
    int i = blockIdx.x * 256 + threadIdx.x;   // 0 .. NP*DM
    int k = i % DM;
    int n = i / DM;
    float v = 0.f;
    if (n < 16)        v = W_B[(size_t)k * DS + n];
    else if (n < 32)   v = W_C[(size_t)k * DS + (n - 16)];
    else if (n < 160)  v = W_dt[(size_t)k * DR + (n - 32)];
    out[i] = (__bf16)v;
}

// ---------------------------------------------------------------------------
// Split packed projection output P (M x NP f32) -> Bp, Cp (f32), dtmp (bf16).
// ---------------------------------------------------------------------------
__global__ void split_proj(const float* __restrict__ P, float* __restrict__ Bp,
                           float* __restrict__ Cp, __bf16* __restrict__ dtmpB) {
    int i = blockIdx.x * 256 + threadIdx.x;   // 0 .. M_*160
    int row = i / 160, c = i % 160;
    float v = P[(size_t)row * NP + c];
    if (c < 16)       Bp[(size_t)row * DS + c] = v;
    else if (c < 32)  Cp[(size_t)row * DS + (c - 16)] = v;
    else              dtmpB[(size_t)row * DR + (c - 32)] = (__bf16)v;
}

// ---------------------------------------------------------------------------
// MFMA bf16 GEMM: C(MxN) = A(MxK) @ B(KxN), BT = B^T (N x K) row-major.
// Wave = 32x32 via 2x2 mfma_f32_16x16x32_bf16; block = 4 waves = 64x64.
// ---------------------------------------------------------------------------
__global__ void gemm_mfma(const __bf16* __restrict__ A, const __bf16* __restrict__ BT,
                          float* __restrict__ Cout, int M, int N, int K) {
    int lane = threadIdx.x & 63;
    int wave = threadIdx.x >> 6;        // 0..3
    int wm = wave >> 1, wn = wave & 1;
    int m0 = blockIdx.y * 64 + wm * 32;
    int n0 = blockIdx.x * 64 + wn * 32;
    int quad = lane >> 4, r = lane & 15;

    f32x4 acc[2][2] = {};

    const __bf16* a0p = A  + (size_t)(m0 +      r) * K + quad * 8;
    const __bf16* a1p = A  + (size_t)(m0 + 16 + r) * K + quad * 8;
    const __bf16* b0p = BT + (size_t)(n0 +      r) * K + quad * 8;
    const __bf16* b1p = BT + (size_t)(n0 + 16 + r) * K + quad * 8;

    for (int k0 = 0; k0 < K; k0 += 32) {
        bf16x8 a0 = *(const bf16x8*)(a0p + k0);
        bf16x8 a1 = *(const bf16x8*)(a1p + k0);
        bf16x8 b0 = *(const bf16x8*)(b0p + k0);
        bf16x8 b1 = *(const bf16x8*)(b1p + k0);
        acc[0][0] = __builtin_amdgcn_mfma_f32_16x16x32_bf16(a0, b0, acc[0][0], 0, 0, 0);
        acc[0][1] = __builtin_amdgcn_mfma_f32_16x16x32_bf16(a0, b1, acc[0][1], 0, 0, 0);
        acc[1][0] = __builtin_amdgcn_mfma_f32_16x16x32_bf16(a1, b0, acc[1][0], 0, 0, 0);
        acc[1][1] = __builtin_amdgcn_mfma_f32_16x16x32_bf16(a1, b1, acc[1][1], 0, 0, 0);
    }

    #pragma unroll
    for (int im = 0; im < 2; im++) {
        #pragma unroll
        for (int in_ = 0; in_ < 2; in_++) {
            int col = n0 + in_ * 16 + r;
            #pragma unroll
            for (int j = 0; j < 4; j++) {
                int row = m0 + im * 16 + quad * 4 + j;
                Cout[(size_t)row * N + col] = acc[im][in_][j];
            }
        }
    }
}

// ---------------------------------------------------------------------------
// MFMA GEMM + bias + softplus epilogue: delta = softplus(A@B + bias[col]).
// ---------------------------------------------------------------------------
__global__ void gemm_mfma_softplus(const __bf16* __restrict__ A, const __bf16* __restrict__ BT,
                                   const float* __restrict__ bias, float* __restrict__ Cout,
                                   int M, int N, int K) {
    int lane = threadIdx.x & 63;
    int wave = threadIdx.x >> 6;
    int wm = wave >> 1, wn = wave & 1;
    int m0 = blockIdx.y * 64 + wm * 32;
    int n0 = blockIdx.x * 64 + wn * 32;
    int quad = lane >> 4, r = lane & 15;

    f32x4 acc[2][2] = {};

    const __bf16* a0p = A  + (size_t)(m0 +      r) * K + quad * 8;
    const __bf16* a1p = A  + (size_t)(m0 + 16 + r) * K + quad * 8;
    const __bf16* b0p = BT + (size_t)(n0 +      r) * K + quad * 8;
    const __bf16* b1p = BT + (size_t)(n0 + 16 + r) * K + quad * 8;

    for (int k0 = 0; k0 < K; k0 += 32) {
        bf16x8 a0 = *(const bf16x8*)(a0p + k0);
        bf16x8 a1 = *(const bf16x8*)(a1p + k0);
        bf16x8 b0 = *(const bf16x8*)(b0p + k0);
        bf16x8 b1 = *(const bf16x8*)(b1p + k0);
        acc[0][0] = __builtin_amdgcn_mfma_f32_16x16x32_bf16(a0, b0, acc[0][0], 0, 0, 0);
        acc[0][1] = __builtin_amdgcn_mfma_f32_16x16x32_bf16(a0, b1, acc[0][1], 0, 0, 0);
        acc[1][0] = __builtin_amdgcn_mfma_f32_16x16x32_bf16(a1, b0, acc[1][0], 0, 0, 0);
        acc[1][1] = __builtin_amdgcn_mfma_f32_16x16x32_bf16(a1, b1, acc[1][1], 0, 0, 0);
    }

    #pragma unroll
    for (int im = 0; im < 2; im++) {
        #pragma unroll
        for (int in_ = 0; in_ < 2; in_++) {
            int col = n0 + in_ * 16 + r;
            float bz = bias[col];
            #pragma unroll
            for (int j = 0; j < 4; j++) {
                int row = m0 + im * 16 + quad * 4 + j;
                float v = acc[im][in_][j] + bz;
                float sp = (v > 20.f) ? v : log1pf(__expf(v));
                Cout[(size_t)row * N + col] = sp;
            }
        }
    }
}

// ---------------------------------------------------------------------------
// Causal depthwise conv (K=4) + bias + SiLU. Emits xc f32 AND xc bf16.
// ---------------------------------------------------------------------------
__global__ void conv_silu(const float* __restrict__ x, const float* __restrict__ w,
                          const float* __restrict__ bias, float* __restrict__ xc,
                          __bf16* __restrict__ xcB) {
    int idx = blockIdx.x * 256 + threadIdx.x;     // 0 .. B*L*DM
    int d  = idx % DM;
    int bl = idx / DM;
    int l  = bl % L_;
    float acc = bias[d];
    #pragma unroll
    for (int i = 0; i < KC; i++) {
        int li = l - (KC - 1) + i;
        if (li >= 0) acc += x[idx + (i - (KC - 1)) * DM] * w[d * KC + i];
    }
    float v = acc / (1.f + __expf(-acc));
    xc[idx] = v;
    xcB[idx] = (__bf16)v;
}

// ---------------------------------------------------------------------------
// Chunked scan, phase 1. Thread owns one (b, dm, chunk): 16 ds states in
// registers. Bp chunk staged in LDS (broadcast reads). No shuffles.
// Grid: B_ * (DM/256) * NC blocks of 256 threads.
// ---------------------------------------------------------------------------
__global__ void scan_phase1(const float* __restrict__ delta, const float* __restrict__ xc,
                            const float* __restrict__ Bp, const float* __restrict__ A_log,
                            float* __restrict__ aprod, float* __restrict__ cend) {
    int blk = blockIdx.x;
    int c   = blk % NC;
    int rem = blk / NC;
    int dmt = rem % (DM / 256);
    int b   = rem / (DM / 256);
    int t   = threadIdx.x;
    int dm  = dmt * 256 + t;
    int l0  = c * CL;

    __shared__ float sB[CL * DS];      // 16x16 = 1 KB
    sB[t] = Bp[((size_t)b * L_ + l0) * DS + t];
    __syncthreads();

    float Aval[DS];
    {
        const f32x4* Ap = (const f32x4*)(A_log + (size_t)dm * DS);
        #pragma unroll
        for (int r4 = 0; r4 < 4; r4++) {
            f32x4 a = Ap[r4];
            #pragma unroll
            for (int q = 0; q < 4; q++) Aval[r4 * 4 + q] = -__expf(a[q]);
        }
    }

    float h[DS], ap[DS];
    #pragma unroll
    for (int i = 0; i < DS; i++) { h[i] = 0.f; ap[i] = 1.f; }

    size_t base = ((size_t)b * L_ + l0) * DM + dm;
    #pragma unroll 4
    for (int j = 0; j < CL; j++) {
        float dl  = delta[base + (size_t)j * DM];
        float xv  = xc[base + (size_t)j * DM];
        float cmn = dl * xv;
        const f32x4* sB4 = (const f32x4*)(sB + j * DS);
        #pragma unroll
        for (int r4 = 0; r4 < 4; r4++) {
            f32x4 bv = sB4[r4];
            #pragma unroll
            for (int q = 0; q < 4; q++) {
                int i = r4 * 4 + q;
                float dA = __expf(dl * Aval[i]);
                ap[i] *= dA;
                h[i] = fmaf(dA, h[i], cmn * bv[q]);
            }
        }
    }

    size_t s = ((size_t)(b * DM + dm)) * DS;
    f32x4* apo = (f32x4*)(aprod + (size_t)c * S_ + s);
    f32x4* ceo = (f32x4*)(cend  + (size_t)c * S_ + s);
    #pragma unroll
    for (int r4 = 0; r4 < 4; r4++) {
        f32x4 va, vh;
        #pragma unroll
        for (int q = 0; q < 4; q++) { va[q] = ap[r4 * 4 + q]; vh[q] = h[r4 * 4 + q]; }
        apo[r4] = va; ceo[r4] = vh;
    }
}

// ---------------------------------------------------------------------------
// Chunked scan, phase 2: scan chunk summaries, emit h_init per chunk.
// ---------------------------------------------------------------------------
__global__ void scan_phase2(const float* __restrict__ aprod, const float* __restrict__ cend,
                            float* __restrict__ hinit) {
    int u = blockIdx.x * 256 + threadIdx.x;   // 0..S_-1
    float h = 0.f;
    #pragma unroll
    for (int c = 0; c < NC; c++) {
        hinit[(size_t)c * S_ + u] = h;
        h = fmaf(aprod[(size_t)c * S_ + u], h, cend[(size_t)c * S_ + u]);
    }
}

// ---------------------------------------------------------------------------
// Chunked scan, phase 3. Thread owns one (b, dm, chunk): replay from exact
// h_init with 16 states in registers, y = sum h*cv in-register, fused
// non-divergent epilogue ybar = (y + D*xc) * silu(res) -> bf16.
// ---------------------------------------------------------------------------
__global__ void scan_phase3(const float* __restrict__ delta, const float* __restrict__ xc,
                            const float* __restrict__ Bp, const float* __restrict__ Cp,
                            const float* __restrict__ res, const float* __restrict__ A_log,
                            const float* __restrict__ Dw, const float* __restrict__ hinit,
                            __bf16* __restrict__ ybar) {
    int blk = blockIdx.x;
    int c   = blk % NC;
    int rem = blk / NC;
    int dmt = rem % (DM / 256);
    int b   = rem / (DM / 256);
    int t   = threadIdx.x;
    int dm  = dmt * 256 + t;
    int l0  = c * CL;

    __shared__ float sB[CL * DS];      // 1 KB
    __shared__ float sC[CL * DS];      // 1 KB
    sB[t] = Bp[((size_t)b * L_ + l0) * DS + t];
    sC[t] = Cp[((size_t)b * L_ + l0) * DS + t];
    __syncthreads();

    float Aval[DS];
    {
        const f32x4* Ap = (const f32x4*)(A_log + (size_t)dm * DS);
        #pragma unroll
        for (int r4 = 0; r4 < 4; r4++) {
            f32x4 a = Ap[r4];
            #pragma unroll
            for (int q = 0; q < 4; q++) Aval[r4 * 4 + q] = -__expf(a[q]);
        }
    }
    float Dval = Dw[dm];

    float h[DS];
    {
        const f32x4* hi = (const f32x4*)(hinit + (size_t)c * S_ + ((size_t)(b * DM + dm)) * DS);
        #pragma unroll
        for (int r4 = 0; r4 < 4; r4++) {
            f32x4 v = hi[r4];
            #pragma unroll
            for (int q = 0; q < 4; q++) h[r4 * 4 + q] = v[q];
        }
    }

    size_t base = ((size_t)b * L_ + l0) * DM + dm;
    #pragma unroll 4
    for (int j = 0; j < CL; j++) {
        float dl  = delta[base + (size_t)j * DM];
        float xv  = xc[base + (size_t)j * DM];
        float rv  = res[base + (size_t)j * DM];
        float cmn = dl * xv;
        float y = 0.f;
        const f32x4* sB4 = (const f32x4*)(sB + j * DS);
        const f32x4* sC4 = (const f32x4*)(sC + j * DS);
        #pragma unroll
        for (int r4 = 0; r4 < 4; r4++) {
            f32x4 bv = sB4[r4];
            f32x4 cv = sC4[r4];
            #pragma unroll
            for (int q = 0; q < 4; q++) {
                int i = r4 * 4 + q;
                float dA = __expf(dl * Aval[i]);
                h[i] = fmaf(dA, h[i], cmn * bv[q]);
                y = fmaf(h[i], cv[q], y);
            }
        }
        float g = rv / (1.f + __expf(-rv));
        ybar[base + (size_t)j * DM] = (__bf16)((y + Dval * xv) * g);
    }
}

// ---------------------------------------------------------------------------
extern "C" void kernel_launch(void* const* d_in, const int* in_sizes, int n_in,
                              void* d_out, int out_size, void* d_ws, size_t ws_size,
                              hipStream_t stream) {
    // All reference tensors are float32.
    const float* x_in   = (const float*)d_in[0];
    const float* W_in   = (const float*)d_in[1];
    const float* W_res  = (const float*)d_in[2];
    const float* W_out  = (const float*)d_in[3];
    const float* conv_w = (const float*)d_in[4];
    const float* conv_b = (const float*)d_in[5];
    const float* A_log  = (const float*)d_in[6];
    const float* Dw     = (const float*)d_in[7];
    const float* W_B    = (const float*)d_in[8];
    const float* W_C    = (const float*)d_in[9];
    const float* W_dt   = (const float*)d_in[10];
    const float* dt_w   = (const float*)d_in[11];
    const float* dt_b   = (const float*)d_in[12];

    // ---------------- Workspace layout ----------------
    float* ws_f = (float*)d_ws;
    float* x     = ws_f;                        // M_*DM
    float* res   = x     + (size_t)M_ * DM;
    float* xc    = res   + (size_t)M_ * DM;
    float* delta = xc    + (size_t)M_ * DM;
    float* P     = delta + (size_t)M_ * DM;     // M_*NP packed projections
    float* Bp    = P     + (size_t)M_ * NP;     // M_*DS
    float* Cp    = Bp    + (size_t)M_ * DS;
    float* aprod = Cp    + (size_t)M_ * DS;     // NC*S_ (16 MB)
    float* cend  = aprod + (size_t)NC * S_;     // NC*S_
    float* hinit = cend  + (size_t)NC * S_;     // NC*S_
    __bf16* bf_base = (__bf16*)(hinit + (size_t)NC * S_);
    __bf16* ybar  = bf_base;                    // M_*DM
    __bf16* xinB  = ybar  + (size_t)M_ * DM;    // M_*DIN
    __bf16* WinT  = xinB  + (size_t)M_ * DIN;   // DM*DIN
    __bf16* WresT = WinT  + (size_t)DM * DIN;
    __bf16* WoutT = WresT + (size_t)DM * DIN;   // DIN*DM
    __bf16* xcB   = WoutT + (size_t)DIN * DM;   // M_*DM
    __bf16* projW = xcB   + (size_t)M_ * DM;    // NP*DM
    __bf16* dtwT  = projW + (size_t)NP * DM;    // DM*DR
    __bf16* dtmpB = dtwT  + (size_t)DM * DR;    // M_*DR

    // ---------------- bf16 operand prep ----------------
    convert_f32_bf16<<<(M_ * DIN) / 256, 256, 0, stream>>>(x_in, xinB, M_ * DIN);
    dim3 tb(32, 8);
    transpose_f32_bf16<<<dim3(DM / 32, DIN / 32), tb, 0, stream>>>(W_in,  WinT,  DIN, DM);
    transpose_f32_bf16<<<dim3(DM / 32, DIN / 32), tb, 0, stream>>>(W_res, WresT, DIN, DM);
    transpose_f32_bf16<<<dim3(DIN / 32, DM / 32), tb, 0, stream>>>(W_out, WoutT, DM, DIN);
    transpose_f32_bf16<<<dim3(DM / 32, DR / 32),  tb, 0, stream>>>(dt_w,  dtwT,  DR, DM);
    pack_projw<<<(NP * DM) / 256, 256, 0, stream>>>(W_B, W_C, W_dt, projW);

    // x = x_in @ W_in ; res = x_in @ W_res   (M_ x DM, K=DIN)
    gemm_mfma<<<dim3(DM / 64, M_ / 64), 256, 0, stream>>>(xinB, WinT,  x,   M_, DM, DIN);
    gemm_mfma<<<dim3(DM / 64, M_ / 64), 256, 0, stream>>>(xinB, WresT, res, M_, DM, DIN);

    conv_silu<<<(M_ * DM) / 256, 256, 0, stream>>>(x, conv_w, conv_b, xc, xcB);

    // Packed projections: P = xc @ [W_B|W_C|W_dt]  (M_ x NP, K=DM)
    gemm_mfma<<<dim3(NP / 64, M_ / 64), 256, 0, stream>>>(xcB, projW, P, M_, NP, DM);
    split_proj<<<(M_ * 160) / 256, 256, 0, stream>>>(P, Bp, Cp, dtmpB);

    // delta = softplus(dtmp @ dt_w + dt_b)  (M_ x DM, K=DR)
    gemm_mfma_softplus<<<dim3(DM / 64, M_ / 64), 256, 0, stream>>>(dtmpB, dtwT, dt_b, delta, M_, DM, DR);

    // Chunked selective scan: thread = (b, dm, chunk), 16 ds states in regs
    int nblk = B_ * (DM / 256) * NC;   // 1024
    scan_phase1<<<nblk, 256, 0, stream>>>(delta, xc, Bp, A_log, aprod, cend);
    scan_phase2<<<S_ / 256, 256, 0, stream>>>(aprod, cend, hinit);
    scan_phase3<<<nblk, 256, 0, stream>>>(delta, xc, Bp, Cp, res, A_log, Dw, hinit, ybar);

    // out = ybar @ W_out  (M_ x DIN, K=DM), f32 output
    gemm_mfma<<<dim3(DIN / 64, M_ / 64), 256, 0, stream>>>(ybar, WoutT, (float*)d_out, M_, DIN, DM);
}

// Round 6
// 331.288 us; speedup vs baseline: 3.4079x; 1.3525x over previous
//
#include <hip/hip_runtime.h>
#include <hip/hip_bf16.h>

// Problem constants
constexpr int B_  = 2;
constexpr int L_  = 1024;
constexpr int DIN = 1024;
constexpr int DM  = 2048;
constexpr int DS  = 16;
constexpr int DR  = 128;
constexpr int KC  = 4;       // conv kernel size
constexpr int M_  = B_ * L_; // 2048 rows
constexpr int NP  = 192;     // packed projection width (16+16+128 padded to 192)

// Chunked scan parameters
constexpr int NC = 64;               // number of chunks
constexpr int CL = L_ / NC;          // chunk length (16)
constexpr int S_ = B_ * DM * DS;     // 65536 scan states

typedef __bf16 bf16x8 __attribute__((ext_vector_type(8)));
typedef float  f32x4  __attribute__((ext_vector_type(4)));

// ---------------------------------------------------------------------------
// async global->LDS 16B copy (global_load_lds_dwordx4).
// LDS dst is wave-uniform base + lane*16 (hardware adds the lane term).
// ---------------------------------------------------------------------------
__device__ __forceinline__ void gload_lds16(const void* g, void* l) {
    __builtin_amdgcn_global_load_lds(
        (const __attribute__((address_space(1))) void*)g,
        (__attribute__((address_space(3))) void*)l, 16, 0, 0);
}

// ---------------------------------------------------------------------------
// f32 -> bf16 elementwise convert
// ---------------------------------------------------------------------------
__global__ void convert_f32_bf16(const float* __restrict__ in, __bf16* __restrict__ out, int n) {
    int i = blockIdx.x * 256 + threadIdx.x;
    if (i < n) out[i] = (__bf16)in[i];
}

// ---------------------------------------------------------------------------
// f32 transpose + bf16 convert: in (R x C) f32 -> out (C x R) bf16.
// ---------------------------------------------------------------------------
__global__ void transpose_f32_bf16(const float* __restrict__ in, __bf16* __restrict__ out,
                                   int R, int C) {
    __shared__ float tile[32][33];
    int bx = blockIdx.x * 32, by = blockIdx.y * 32;
    int tx = threadIdx.x, ty = threadIdx.y; // (32, 8)
    #pragma unroll
    for (int j = 0; j < 32; j += 8) {
        tile[ty + j][tx] = in[(size_t)(by + ty + j) * C + (bx + tx)];
    }
    __syncthreads();
    #pragma unroll
    for (int j = 0; j < 32; j += 8) {
        out[(size_t)(bx + ty + j) * R + (by + tx)] = (__bf16)tile[tx][ty + j];
    }
}

// ---------------------------------------------------------------------------
// Pack [W_B | W_C | W_dt | 0] into BT form: out (NP x DM) bf16.
// ---------------------------------------------------------------------------
__global__ void pack_projw(const float* __restrict__ W_B, const float* __restrict__ W_C,
                           const float* __restrict__ W_dt, __bf16* __restrict__ out) {
    int i = blockIdx.x * 256 + threadIdx.x;   // 0 .. NP*DM
    int k = i % DM;
    int n = i / DM;
    float v = 0.f;
    if (n < 16)        v = W_B[(size_t)k * DS + n];
    else if (n < 32)   v = W_C[(size_t)k * DS + (n - 16)];
    else if (n < 160)  v = W_dt[(size_t)k * DR + (n - 32)];
    out[i] = (__bf16)v;
}

// ---------------------------------------------------------------------------
// Split packed projection output P (M x NP f32) -> Bp, Cp (f32), dtmp (bf16).
// ---------------------------------------------------------------------------
__global__ void split_proj(const float* __restrict__ P, float* __restrict__ Bp,
                           float* __restrict__ Cp, __bf16* __restrict__ dtmpB) {
    int i = blockIdx.x * 256 + threadIdx.x;   // 0 .. M_*160
    int row = i / 160, c = i % 160;
    float v = P[(size_t)row * NP + c];
    if (c < 16)       Bp[(size_t)row * DS + c] = v;
    else if (c < 32)  Cp[(size_t)row * DS + (c - 16)] = v;
    else              dtmpB[(size_t)row * DR + (c - 32)] = (__bf16)v;
}

// ---------------------------------------------------------------------------
// m97-style MFMA GEMM: 128x128 block tile, BK=32, LDS-staged via
// global_load_lds width=16, XOR-swizzled slots (conflict-free ds_read_b128).
// 4 waves, each 64x64 (4x4 of 16x16x32 MFMA).
// EPI: 0 = plain f32 store (stride N); 1 = +bias[col] softplus (stride N);
//      2 = split dual-output: col<DM -> C0 else C1, row stride DM.
// Requires: M%128==0, N%128==0, K%32==0.
// ---------------------------------------------------------------------------
template<int EPI>
__global__ void gemm_tile128(const __bf16* __restrict__ A, const __bf16* __restrict__ BT,
                             float* __restrict__ C0, float* __restrict__ C1,
                             const float* __restrict__ bias, int M, int N, int K) {
    __shared__ __bf16 sA[128 * 32];
    __shared__ __bf16 sB[128 * 32];
    int t = threadIdx.x;
    int lane = t & 63, w = t >> 6;
    int wm = w >> 1, wn = w & 1;
    int m0 = blockIdx.y * 128, n0 = blockIdx.x * 128;
    int q = lane >> 4, rr = lane & 15;

    f32x4 acc[4][4] = {};

    int srow = t >> 2;          // 0..63 (staging row, +64 on round 1)
    int slot = t & 3;           // physical 8-elem slot within the 32-wide k

    for (int kt = 0; kt < K; kt += 32) {
        __syncthreads();
        #pragma unroll
        for (int rnd = 0; rnd < 2; rnd++) {
            int row = srow + rnd * 64;
            int gkb = slot ^ ((row >> 1) & 3);          // logical k-block fetched into this slot
            const __bf16* ga = A  + (size_t)(m0 + row) * K + kt + gkb * 8;
            const __bf16* gb = BT + (size_t)(n0 + row) * K + kt + gkb * 8;
            __bf16* la = sA + rnd * 2048 + w * 512;     // wave-uniform base
            __bf16* lb = sB + rnd * 2048 + w * 512;
            gload_lds16(ga, la);
            gload_lds16(gb, lb);
        }
        __syncthreads();

        bf16x8 af[4], bfr[4];
        #pragma unroll
        for (int i = 0; i < 4; i++) {
            int rowA = wm * 64 + i * 16 + rr;
            af[i] = *(const bf16x8*)(sA + rowA * 32 + ((q ^ ((rowA >> 1) & 3)) * 8));
            int rowB = wn * 64 + i * 16 + rr;
            bfr[i] = *(const bf16x8*)(sB + rowB * 32 + ((q ^ ((rowB >> 1) & 3)) * 8));
        }
        #pragma unroll
        for (int i = 0; i < 4; i++)
            #pragma unroll
            for (int j = 0; j < 4; j++)
                acc[i][j] = __builtin_amdgcn_mfma_f32_16x16x32_bf16(af[i], bfr[j], acc[i][j], 0, 0, 0);
    }

    #pragma unroll
    for (int i = 0; i < 4; i++) {
        #pragma unroll
        for (int j = 0; j < 4; j++) {
            int col = n0 + wn * 64 + j * 16 + rr;
            #pragma unroll
            for (int jj = 0; jj < 4; jj++) {
                int row = m0 + wm * 64 + i * 16 + q * 4 + jj;
                float v = acc[i][j][jj];
                if (EPI == 0) {
                    C0[(size_t)row * N + col] = v;
                } else if (EPI == 1) {
                    float z = v + bias[col];
                    C0[(size_t)row * N + col] = (z > 20.f) ? z : log1pf(__expf(z));
                } else {
                    float* o = (col < DM) ? C0 : C1;
                    o[(size_t)row * DM + (col & (DM - 1))] = v;
                }
            }
        }
    }
}

// ---------------------------------------------------------------------------
// 64x64 MFMA GEMM (direct loads) — kept for the narrow proj GEMM (N=192).
// ---------------------------------------------------------------------------
__global__ void gemm_mfma(const __bf16* __restrict__ A, const __bf16* __restrict__ BT,
                          float* __restrict__ Cout, int M, int N, int K) {
    int lane = threadIdx.x & 63;
    int wave = threadIdx.x >> 6;        // 0..3
    int wm = wave >> 1, wn = wave & 1;
    int m0 = blockIdx.y * 64 + wm * 32;
    int n0 = blockIdx.x * 64 + wn * 32;
    int quad = lane >> 4, r = lane & 15;

    f32x4 acc[2][2] = {};

    const __bf16* a0p = A  + (size_t)(m0 +      r) * K + quad * 8;
    const __bf16* a1p = A  + (size_t)(m0 + 16 + r) * K + quad * 8;
    const __bf16* b0p = BT + (size_t)(n0 +      r) * K + quad * 8;
    const __bf16* b1p = BT + (size_t)(n0 + 16 + r) * K + quad * 8;

    for (int k0 = 0; k0 < K; k0 += 32) {
        bf16x8 a0 = *(const bf16x8*)(a0p + k0);
        bf16x8 a1 = *(const bf16x8*)(a1p + k0);
        bf16x8 b0 = *(const bf16x8*)(b0p + k0);
        bf16x8 b1 = *(const bf16x8*)(b1p + k0);
        acc[0][0] = __builtin_amdgcn_mfma_f32_16x16x32_bf16(a0, b0, acc[0][0], 0, 0, 0);
        acc[0][1] = __builtin_amdgcn_mfma_f32_16x16x32_bf16(a0, b1, acc[0][1], 0, 0, 0);
        acc[1][0] = __builtin_amdgcn_mfma_f32_16x16x32_bf16(a1, b0, acc[1][0], 0, 0, 0);
        acc[1][1] = __builtin_amdgcn_mfma_f32_16x16x32_bf16(a1, b1, acc[1][1], 0, 0, 0);
    }

    #pragma unroll
    for (int im = 0; im < 2; im++) {
        #pragma unroll
        for (int in_ = 0; in_ < 2; in_++) {
            int col = n0 + in_ * 16 + r;
            #pragma unroll
            for (int j = 0; j < 4; j++) {
                int row = m0 + im * 16 + quad * 4 + j;
                Cout[(size_t)row * N + col] = acc[im][in_][j];
            }
        }
    }
}

// ---------------------------------------------------------------------------
// Causal depthwise conv (K=4) + bias + SiLU. Emits xc f32 AND xc bf16.
// ---------------------------------------------------------------------------
__global__ void conv_silu(const float* __restrict__ x, const float* __restrict__ w,
                          const float* __restrict__ bias, float* __restrict__ xc,
                          __bf16* __restrict__ xcB) {
    int idx = blockIdx.x * 256 + threadIdx.x;     // 0 .. B*L*DM
    int d  = idx % DM;
    int bl = idx / DM;
    int l  = bl % L_;
    float acc = bias[d];
    #pragma unroll
    for (int i = 0; i < KC; i++) {
        int li = l - (KC - 1) + i;
        if (li >= 0) acc += x[idx + (i - (KC - 1)) * DM] * w[d * KC + i];
    }
    float v = acc / (1.f + __expf(-acc));
    xc[idx] = v;
    xcB[idx] = (__bf16)v;
}

// ---------------------------------------------------------------------------
// Chunked scan, phase 1. Thread owns one (b, dm, chunk): 16 ds states in regs.
// ---------------------------------------------------------------------------
__global__ void scan_phase1(const float* __restrict__ delta, const float* __restrict__ xc,
                            const float* __restrict__ Bp, const float* __restrict__ A_log,
                            float* __restrict__ aprod, float* __restrict__ cend) {
    int blk = blockIdx.x;
    int c   = blk % NC;
    int rem = blk / NC;
    int dmt = rem % (DM / 256);
    int b   = rem / (DM / 256);
    int t   = threadIdx.x;
    int dm  = dmt * 256 + t;
    int l0  = c * CL;

    __shared__ float sB[CL * DS];      // 16x16 = 1 KB
    sB[t] = Bp[((size_t)b * L_ + l0) * DS + t];
    __syncthreads();

    float Aval[DS];
    {
        const f32x4* Ap = (const f32x4*)(A_log + (size_t)dm * DS);
        #pragma unroll
        for (int r4 = 0; r4 < 4; r4++) {
            f32x4 a = Ap[r4];
            #pragma unroll
            for (int q = 0; q < 4; q++) Aval[r4 * 4 + q] = -__expf(a[q]);
        }
    }

    float h[DS], ap[DS];
    #pragma unroll
    for (int i = 0; i < DS; i++) { h[i] = 0.f; ap[i] = 1.f; }

    size_t base = ((size_t)b * L_ + l0) * DM + dm;
    #pragma unroll 4
    for (int j = 0; j < CL; j++) {
        float dl  = delta[base + (size_t)j * DM];
        float xv  = xc[base + (size_t)j * DM];
        float cmn = dl * xv;
        const f32x4* sB4 = (const f32x4*)(sB + j * DS);
        #pragma unroll
        for (int r4 = 0; r4 < 4; r4++) {
            f32x4 bv = sB4[r4];
            #pragma unroll
            for (int q = 0; q < 4; q++) {
                int i = r4 * 4 + q;
                float dA = __expf(dl * Aval[i]);
                ap[i] *= dA;
                h[i] = fmaf(dA, h[i], cmn * bv[q]);
            }
        }
    }

    size_t s = ((size_t)(b * DM + dm)) * DS;
    f32x4* apo = (f32x4*)(aprod + (size_t)c * S_ + s);
    f32x4* ceo = (f32x4*)(cend  + (size_t)c * S_ + s);
    #pragma unroll
    for (int r4 = 0; r4 < 4; r4++) {
        f32x4 va, vh;
        #pragma unroll
        for (int q = 0; q < 4; q++) { va[q] = ap[r4 * 4 + q]; vh[q] = h[r4 * 4 + q]; }
        apo[r4] = va; ceo[r4] = vh;
    }
}

// ---------------------------------------------------------------------------
// Chunked scan, phase 2: scan chunk summaries, emit h_init per chunk.
// ---------------------------------------------------------------------------
__global__ void scan_phase2(const float* __restrict__ aprod, const float* __restrict__ cend,
                            float* __restrict__ hinit) {
    int u = blockIdx.x * 256 + threadIdx.x;   // 0..S_-1
    float h = 0.f;
    #pragma unroll
    for (int c = 0; c < NC; c++) {
        hinit[(size_t)c * S_ + u] = h;
        h = fmaf(aprod[(size_t)c * S_ + u], h, cend[(size_t)c * S_ + u]);
    }
}

// ---------------------------------------------------------------------------
// Chunked scan, phase 3: replay from exact h_init, fused epilogue -> bf16.
// ---------------------------------------------------------------------------
__global__ void scan_phase3(const float* __restrict__ delta, const float* __restrict__ xc,
                            const float* __restrict__ Bp, const float* __restrict__ Cp,
                            const float* __restrict__ res, const float* __restrict__ A_log,
                            const float* __restrict__ Dw, const float* __restrict__ hinit,
                            __bf16* __restrict__ ybar) {
    int blk = blockIdx.x;
    int c   = blk % NC;
    int rem = blk / NC;
    int dmt = rem % (DM / 256);
    int b   = rem / (DM / 256);
    int t   = threadIdx.x;
    int dm  = dmt * 256 + t;
    int l0  = c * CL;

    __shared__ float sB[CL * DS];      // 1 KB
    __shared__ float sC[CL * DS];      // 1 KB
    sB[t] = Bp[((size_t)b * L_ + l0) * DS + t];
    sC[t] = Cp[((size_t)b * L_ + l0) * DS + t];
    __syncthreads();

    float Aval[DS];
    {
        const f32x4* Ap = (const f32x4*)(A_log + (size_t)dm * DS);
        #pragma unroll
        for (int r4 = 0; r4 < 4; r4++) {
            f32x4 a = Ap[r4];
            #pragma unroll
            for (int q = 0; q < 4; q++) Aval[r4 * 4 + q] = -__expf(a[q]);
        }
    }
    float Dval = Dw[dm];

    float h[DS];
    {
        const f32x4* hi = (const f32x4*)(hinit + (size_t)c * S_ + ((size_t)(b * DM + dm)) * DS);
        #pragma unroll
        for (int r4 = 0; r4 < 4; r4++) {
            f32x4 v = hi[r4];
            #pragma unroll
            for (int q = 0; q < 4; q++) h[r4 * 4 + q] = v[q];
        }
    }

    size_t base = ((size_t)b * L_ + l0) * DM + dm;
    #pragma unroll 4
    for (int j = 0; j < CL; j++) {
        float dl  = delta[base + (size_t)j * DM];
        float xv  = xc[base + (size_t)j * DM];
        float rv  = res[base + (size_t)j * DM];
        float cmn = dl * xv;
        float y = 0.f;
        const f32x4* sB4 = (const f32x4*)(sB + j * DS);
        const f32x4* sC4 = (const f32x4*)(sC + j * DS);
        #pragma unroll
        for (int r4 = 0; r4 < 4; r4++) {
            f32x4 bv = sB4[r4];
            f32x4 cv = sC4[r4];
            #pragma unroll
            for (int q = 0; q < 4; q++) {
                int i = r4 * 4 + q;
                float dA = __expf(dl * Aval[i]);
                h[i] = fmaf(dA, h[i], cmn * bv[q]);
                y = fmaf(h[i], cv[q], y);
            }
        }
        float g = rv / (1.f + __expf(-rv));
        ybar[base + (size_t)j * DM] = (__bf16)((y + Dval * xv) * g);
    }
}

// ---------------------------------------------------------------------------
extern "C" void kernel_launch(void* const* d_in, const int* in_sizes, int n_in,
                              void* d_out, int out_size, void* d_ws, size_t ws_size,
                              hipStream_t stream) {
    // All reference tensors are float32.
    const float* x_in   = (const float*)d_in[0];
    const float* W_in   = (const float*)d_in[1];
    const float* W_res  = (const float*)d_in[2];
    const float* W_out  = (const float*)d_in[3];
    const float* conv_w = (const float*)d_in[4];
    const float* conv_b = (const float*)d_in[5];
    const float* A_log  = (const float*)d_in[6];
    const float* Dw     = (const float*)d_in[7];
    const float* W_B    = (const float*)d_in[8];
    const float* W_C    = (const float*)d_in[9];
    const float* W_dt   = (const float*)d_in[10];
    const float* dt_w   = (const float*)d_in[11];
    const float* dt_b   = (const float*)d_in[12];

    // ---------------- Workspace layout ----------------
    float* ws_f = (float*)d_ws;
    float* x     = ws_f;                        // M_*DM
    float* res   = x     + (size_t)M_ * DM;
    float* xc    = res   + (size_t)M_ * DM;
    float* delta = xc    + (size_t)M_ * DM;
    float* P     = delta + (size_t)M_ * DM;     // M_*NP packed projections
    float* Bp    = P     + (size_t)M_ * NP;     // M_*DS
    float* Cp    = Bp    + (size_t)M_ * DS;
    float* aprod = Cp    + (size_t)M_ * DS;     // NC*S_
    float* cend  = aprod + (size_t)NC * S_;     // NC*S_
    float* hinit = cend  + (size_t)NC * S_;     // NC*S_
    __bf16* bf_base = (__bf16*)(hinit + (size_t)NC * S_);
    __bf16* ybar  = bf_base;                    // M_*DM
    __bf16* xinB  = ybar  + (size_t)M_ * DM;    // M_*DIN
    __bf16* WinT  = xinB  + (size_t)M_ * DIN;   // DM*DIN  } adjacent: forms the
    __bf16* WresT = WinT  + (size_t)DM * DIN;   // DM*DIN  } fused (4096 x DIN) BT
    __bf16* WoutT = WresT + (size_t)DM * DIN;   // DIN*DM
    __bf16* xcB   = WoutT + (size_t)DIN * DM;   // M_*DM
    __bf16* projW = xcB   + (size_t)M_ * DM;    // NP*DM
    __bf16* dtwT  = projW + (size_t)NP * DM;    // DM*DR
    __bf16* dtmpB = dtwT  + (size_t)DM * DR;    // M_*DR

    // ---------------- bf16 operand prep ----------------
    convert_f32_bf16<<<(M_ * DIN) / 256, 256, 0, stream>>>(x_in, xinB, M_ * DIN);
    dim3 tb(32, 8);
    transpose_f32_bf16<<<dim3(DM / 32, DIN / 32), tb, 0, stream>>>(W_in,  WinT,  DIN, DM);
    transpose_f32_bf16<<<dim3(DM / 32, DIN / 32), tb, 0, stream>>>(W_res, WresT, DIN, DM);
    transpose_f32_bf16<<<dim3(DIN / 32, DM / 32), tb, 0, stream>>>(W_out, WoutT, DM, DIN);
    transpose_f32_bf16<<<dim3(DM / 32, DR / 32),  tb, 0, stream>>>(dt_w,  dtwT,  DR, DM);
    pack_projw<<<(NP * DM) / 256, 256, 0, stream>>>(W_B, W_C, W_dt, projW);

    // Fused input GEMMs: [x | res] = x_in @ [W_in | W_res]  (M_ x 4096, K=DIN)
    gemm_tile128<2><<<dim3((2 * DM) / 128, M_ / 128), 256, 0, stream>>>(
        xinB, WinT, x, res, nullptr, M_, 2 * DM, DIN);

    conv_silu<<<(M_ * DM) / 256, 256, 0, stream>>>(x, conv_w, conv_b, xc, xcB);

    // Packed projections: P = xc @ [W_B|W_C|W_dt]  (M_ x NP, K=DM)
    gemm_mfma<<<dim3(NP / 64, M_ / 64), 256, 0, stream>>>(xcB, projW, P, M_, NP, DM);
    split_proj<<<(M_ * 160) / 256, 256, 0, stream>>>(P, Bp, Cp, dtmpB);

    // delta = softplus(dtmp @ dt_w + dt_b)  (M_ x DM, K=DR)
    gemm_tile128<1><<<dim3(DM / 128, M_ / 128), 256, 0, stream>>>(
        dtmpB, dtwT, delta, nullptr, dt_b, M_, DM, DR);

    // Chunked selective scan
    int nblk = B_ * (DM / 256) * NC;   // 1024
    scan_phase1<<<nblk, 256, 0, stream>>>(delta, xc, Bp, A_log, aprod, cend);
    scan_phase2<<<S_ / 256, 256, 0, stream>>>(aprod, cend, hinit);
    scan_phase3<<<nblk, 256, 0, stream>>>(delta, xc, Bp, Cp, res, A_log, Dw, hinit, ybar);

    // out = ybar @ W_out  (M_ x DIN, K=DM), f32 output
    gemm_tile128<0><<<dim3(DIN / 128, M_ / 128), 256, 0, stream>>>(
        ybar, WoutT, (float*)d_out, nullptr, nullptr, M_, DIN, DM);
}

// Round 7
// 292.215 us; speedup vs baseline: 3.8636x; 1.1337x over previous
//
#include <hip/hip_runtime.h>
#include <hip/hip_bf16.h>

// Problem constants
constexpr int B_  = 2;
constexpr int L_  = 1024;
constexpr int DIN = 1024;
constexpr int DM  = 2048;
constexpr int DS  = 16;
constexpr int DR  = 128;
constexpr int KC  = 4;       // conv kernel size
constexpr int M_  = B_ * L_; // 2048 rows
constexpr int NP2 = 256;     // packed projection width (16+16+128 padded to 256)
constexpr int KSLICES = 8;   // split-K for proj GEMM
constexpr int KSL = DM / KSLICES; // 256

// Chunked scan parameters
constexpr int NC = 64;               // number of chunks
constexpr int CL = L_ / NC;          // chunk length (16)
constexpr int S_ = B_ * DM * DS;     // 65536 scan states

typedef __bf16 bf16x8 __attribute__((ext_vector_type(8)));
typedef float  f32x4  __attribute__((ext_vector_type(4)));

// ---------------------------------------------------------------------------
// async global->LDS 16B copy (global_load_lds_dwordx4).
// LDS dst is wave-uniform base + lane*16 (hardware adds the lane term).
// ---------------------------------------------------------------------------
__device__ __forceinline__ void gload_lds16(const void* g, void* l) {
    __builtin_amdgcn_global_load_lds(
        (const __attribute__((address_space(1))) void*)g,
        (__attribute__((address_space(3))) void*)l, 16, 0, 0);
}

// ---------------------------------------------------------------------------
// Fused operand prep: one launch does
//   [0, 8192)        : convert x_in f32 -> xinB bf16
//   [8192, 10240)    : transpose W_in  (DIN x DM) -> WinT  (DM x DIN)
//   [10240, 12288)   : transpose W_res -> WresT
//   [12288, 14336)   : transpose W_out (DM x DIN) -> WoutT (DIN x DM)
//   [14336, 14592)   : transpose dt_w  (DR x DM)  -> dtwT  (DM x DR)
//   [14592, 16640)   : pack [W_B|W_C|W_dt|0] -> projW (NP2 x DM)
// ---------------------------------------------------------------------------
__device__ __forceinline__ void transpose_block(const float* __restrict__ in,
                                                __bf16* __restrict__ out,
                                                int R, int C, int bx, int by, int t) {
    __shared__ float tile[32][33];
    int tx = t & 31, ty = t >> 5;   // (32, 8)
    #pragma unroll
    for (int j = 0; j < 32; j += 8)
        tile[ty + j][tx] = in[(size_t)(by * 32 + ty + j) * C + (bx * 32 + tx)];
    __syncthreads();
    #pragma unroll
    for (int j = 0; j < 32; j += 8)
        out[(size_t)(bx * 32 + ty + j) * R + (by * 32 + tx)] = (__bf16)tile[tx][ty + j];
}

__global__ void prep_all(const float* __restrict__ x_in, const float* __restrict__ W_in,
                         const float* __restrict__ W_res, const float* __restrict__ W_out,
                         const float* __restrict__ dt_w,
                         const float* __restrict__ W_B, const float* __restrict__ W_C,
                         const float* __restrict__ W_dt,
                         __bf16* __restrict__ xinB, __bf16* __restrict__ WinT,
                         __bf16* __restrict__ WresT, __bf16* __restrict__ WoutT,
                         __bf16* __restrict__ dtwT, __bf16* __restrict__ projW) {
    int blk = blockIdx.x, t = threadIdx.x;
    if (blk < 8192) {
        int i = blk * 256 + t;
        xinB[i] = (__bf16)x_in[i];
    } else if (blk < 10240) {
        int b = blk - 8192;                       // grid (64, 32)
        transpose_block(W_in, WinT, DIN, DM, b % 64, b / 64, t);
    } else if (blk < 12288) {
        int b = blk - 10240;
        transpose_block(W_res, WresT, DIN, DM, b % 64, b / 64, t);
    } else if (blk < 14336) {
        int b = blk - 12288;                      // grid (32, 64)
        transpose_block(W_out, WoutT, DM, DIN, b % 32, b / 32, t);
    } else if (blk < 14592) {
        int b = blk - 14336;                      // grid (64, 4)
        transpose_block(dt_w, dtwT, DR, DM, b % 64, b / 64, t);
    } else {
        int i = (blk - 14592) * 256 + t;          // 0 .. NP2*DM
        int k = i % DM;
        int n = i / DM;
        float v = 0.f;
        if (n < 16)        v = W_B[(size_t)k * DS + n];
        else if (n < 32)   v = W_C[(size_t)k * DS + (n - 16)];
        else if (n < 160)  v = W_dt[(size_t)k * DR + (n - 32)];
        projW[i] = (__bf16)v;
    }
}

// ---------------------------------------------------------------------------
// Reduce split-K partials and route: Bp, Cp (f32), dtmp (bf16).
// ---------------------------------------------------------------------------
__global__ void reduce_split(const float* __restrict__ Ppart, float* __restrict__ Bp,
                             float* __restrict__ Cp, __bf16* __restrict__ dtmpB) {
    int i = blockIdx.x * 256 + threadIdx.x;   // 0 .. M_*160
    int row = i / 160, c = i % 160;
    float v = 0.f;
    #pragma unroll
    for (int ks = 0; ks < KSLICES; ks++)
        v += Ppart[(size_t)ks * M_ * NP2 + (size_t)row * NP2 + c];
    if (c < 16)       Bp[(size_t)row * DS + c] = v;
    else if (c < 32)  Cp[(size_t)row * DS + (c - 16)] = v;
    else              dtmpB[(size_t)row * DR + (c - 32)] = (__bf16)v;
}

// ---------------------------------------------------------------------------
// m97-style MFMA GEMM: 128x128 block tile, BK=32, LDS-staged via
// global_load_lds width=16, XOR-swizzled slots (conflict-free ds_read_b128).
// 4 waves, each 64x64 (4x4 of 16x16x32 MFMA). blockIdx.z = K-slice (split-K):
// reads columns [z*K, (z+1)*K), writes C0 + z*M*N (EPI 0 only).
// EPI: 0 = plain f32 store (stride N); 1 = +bias[col] softplus (stride N);
//      2 = split dual-output: col<DM -> C0 else C1, row stride DM.
// Requires: M%128==0, N%128==0, K%32==0.
// ---------------------------------------------------------------------------
template<int EPI>
__global__ void gemm_tile128(const __bf16* __restrict__ A, const __bf16* __restrict__ BT,
                             float* __restrict__ C0, float* __restrict__ C1,
                             const float* __restrict__ bias, int M, int N, int K,
                             int lda, int ldb) {
    __shared__ __bf16 sA[128 * 32];
    __shared__ __bf16 sB[128 * 32];
    int t = threadIdx.x;
    int lane = t & 63, w = t >> 6;
    int wm = w >> 1, wn = w & 1;
    int m0 = blockIdx.y * 128, n0 = blockIdx.x * 128;
    int kbase = blockIdx.z * K;
    int q = lane >> 4, rr = lane & 15;

    f32x4 acc[4][4] = {};

    int srow = t >> 2;          // 0..63 (staging row, +64 on round 1)
    int slot = t & 3;           // physical 8-elem slot within the 32-wide k

    for (int kt = 0; kt < K; kt += 32) {
        __syncthreads();
        #pragma unroll
        for (int rnd = 0; rnd < 2; rnd++) {
            int row = srow + rnd * 64;
            int gkb = slot ^ ((row >> 1) & 3);          // logical k-block fetched into this slot
            const __bf16* ga = A  + (size_t)(m0 + row) * lda + kbase + kt + gkb * 8;
            const __bf16* gb = BT + (size_t)(n0 + row) * ldb + kbase + kt + gkb * 8;
            __bf16* la = sA + rnd * 2048 + w * 512;     // wave-uniform base
            __bf16* lb = sB + rnd * 2048 + w * 512;
            gload_lds16(ga, la);
            gload_lds16(gb, lb);
        }
        __syncthreads();

        bf16x8 af[4], bfr[4];
        #pragma unroll
        for (int i = 0; i < 4; i++) {
            int rowA = wm * 64 + i * 16 + rr;
            af[i] = *(const bf16x8*)(sA + rowA * 32 + ((q ^ ((rowA >> 1) & 3)) * 8));
            int rowB = wn * 64 + i * 16 + rr;
            bfr[i] = *(const bf16x8*)(sB + rowB * 32 + ((q ^ ((rowB >> 1) & 3)) * 8));
        }
        #pragma unroll
        for (int i = 0; i < 4; i++)
            #pragma unroll
            for (int j = 0; j < 4; j++)
                acc[i][j] = __builtin_amdgcn_mfma_f32_16x16x32_bf16(af[i], bfr[j], acc[i][j], 0, 0, 0);
    }

    float* Cz = C0 + (size_t)blockIdx.z * M * N;
    #pragma unroll
    for (int i = 0; i < 4; i++) {
        #pragma unroll
        for (int j = 0; j < 4; j++) {
            int col = n0 + wn * 64 + j * 16 + rr;
            #pragma unroll
            for (int jj = 0; jj < 4; jj++) {
                int row = m0 + wm * 64 + i * 16 + q * 4 + jj;
                float v = acc[i][j][jj];
                if (EPI == 0) {
                    Cz[(size_t)row * N + col] = v;
                } else if (EPI == 1) {
                    float z = v + bias[col];
                    C0[(size_t)row * N + col] = (z > 20.f) ? z : log1pf(__expf(z));
                } else {
                    float* o = (col < DM) ? C0 : C1;
                    o[(size_t)row * DM + (col & (DM - 1))] = v;
                }
            }
        }
    }
}

// ---------------------------------------------------------------------------
// Causal depthwise conv (K=4) + bias + SiLU. Emits xc f32 AND xc bf16.
// ---------------------------------------------------------------------------
__global__ void conv_silu(const float* __restrict__ x, const float* __restrict__ w,
                          const float* __restrict__ bias, float* __restrict__ xc,
                          __bf16* __restrict__ xcB) {
    int idx = blockIdx.x * 256 + threadIdx.x;     // 0 .. B*L*DM
    int d  = idx % DM;
    int bl = idx / DM;
    int l  = bl % L_;
    float acc = bias[d];
    #pragma unroll
    for (int i = 0; i < KC; i++) {
        int li = l - (KC - 1) + i;
        if (li >= 0) acc += x[idx + (i - (KC - 1)) * DM] * w[d * KC + i];
    }
    float v = acc / (1.f + __expf(-acc));
    xc[idx] = v;
    xcB[idx] = (__bf16)v;
}

// ---------------------------------------------------------------------------
// Chunked scan, phase 1. Thread owns one (b, dm, chunk): 16 ds states in regs.
// ---------------------------------------------------------------------------
__global__ void scan_phase1(const float* __restrict__ delta, const float* __restrict__ xc,
                            const float* __restrict__ Bp, const float* __restrict__ A_log,
                            float* __restrict__ aprod, float* __restrict__ cend) {
    int blk = blockIdx.x;
    int c   = blk % NC;
    int rem = blk / NC;
    int dmt = rem % (DM / 256);
    int b   = rem / (DM / 256);
    int t   = threadIdx.x;
    int dm  = dmt * 256 + t;
    int l0  = c * CL;

    __shared__ float sB[CL * DS];      // 16x16 = 1 KB
    sB[t] = Bp[((size_t)b * L_ + l0) * DS + t];
    __syncthreads();

    float Aval[DS];
    {
        const f32x4* Ap = (const f32x4*)(A_log + (size_t)dm * DS);
        #pragma unroll
        for (int r4 = 0; r4 < 4; r4++) {
            f32x4 a = Ap[r4];
            #pragma unroll
            for (int q = 0; q < 4; q++) Aval[r4 * 4 + q] = -__expf(a[q]);
        }
    }

    float h[DS], ap[DS];
    #pragma unroll
    for (int i = 0; i < DS; i++) { h[i] = 0.f; ap[i] = 1.f; }

    size_t base = ((size_t)b * L_ + l0) * DM + dm;
    #pragma unroll 4
    for (int j = 0; j < CL; j++) {
        float dl  = delta[base + (size_t)j * DM];
        float xv  = xc[base + (size_t)j * DM];
        float cmn = dl * xv;
        const f32x4* sB4 = (const f32x4*)(sB + j * DS);
        #pragma unroll
        for (int r4 = 0; r4 < 4; r4++) {
            f32x4 bv = sB4[r4];
            #pragma unroll
            for (int q = 0; q < 4; q++) {
                int i = r4 * 4 + q;
                float dA = __expf(dl * Aval[i]);
                ap[i] *= dA;
                h[i] = fmaf(dA, h[i], cmn * bv[q]);
            }
        }
    }

    size_t s = ((size_t)(b * DM + dm)) * DS;
    f32x4* apo = (f32x4*)(aprod + (size_t)c * S_ + s);
    f32x4* ceo = (f32x4*)(cend  + (size_t)c * S_ + s);
    #pragma unroll
    for (int r4 = 0; r4 < 4; r4++) {
        f32x4 va, vh;
        #pragma unroll
        for (int q = 0; q < 4; q++) { va[q] = ap[r4 * 4 + q]; vh[q] = h[r4 * 4 + q]; }
        apo[r4] = va; ceo[r4] = vh;
    }
}

// ---------------------------------------------------------------------------
// Chunked scan, phase 2: scan chunk summaries, emit h_init per chunk.
// ---------------------------------------------------------------------------
__global__ void scan_phase2(const float* __restrict__ aprod, const float* __restrict__ cend,
                            float* __restrict__ hinit) {
    int u = blockIdx.x * 256 + threadIdx.x;   // 0..S_-1
    float h = 0.f;
    #pragma unroll
    for (int c = 0; c < NC; c++) {
        hinit[(size_t)c * S_ + u] = h;
        h = fmaf(aprod[(size_t)c * S_ + u], h, cend[(size_t)c * S_ + u]);
    }
}

// ---------------------------------------------------------------------------
// Chunked scan, phase 3: replay from exact h_init, fused epilogue -> bf16.
// ---------------------------------------------------------------------------
__global__ void scan_phase3(const float* __restrict__ delta, const float* __restrict__ xc,
                            const float* __restrict__ Bp, const float* __restrict__ Cp,
                            const float* __restrict__ res, const float* __restrict__ A_log,
                            const float* __restrict__ Dw, const float* __restrict__ hinit,
                            __bf16* __restrict__ ybar) {
    int blk = blockIdx.x;
    int c   = blk % NC;
    int rem = blk / NC;
    int dmt = rem % (DM / 256);
    int b   = rem / (DM / 256);
    int t   = threadIdx.x;
    int dm  = dmt * 256 + t;
    int l0  = c * CL;

    __shared__ float sB[CL * DS];      // 1 KB
    __shared__ float sC[CL * DS];      // 1 KB
    sB[t] = Bp[((size_t)b * L_ + l0) * DS + t];
    sC[t] = Cp[((size_t)b * L_ + l0) * DS + t];
    __syncthreads();

    float Aval[DS];
    {
        const f32x4* Ap = (const f32x4*)(A_log + (size_t)dm * DS);
        #pragma unroll
        for (int r4 = 0; r4 < 4; r4++) {
            f32x4 a = Ap[r4];
            #pragma unroll
            for (int q = 0; q < 4; q++) Aval[r4 * 4 + q] = -__expf(a[q]);
        }
    }
    float Dval = Dw[dm];

    float h[DS];
    {
        const f32x4* hi = (const f32x4*)(hinit + (size_t)c * S_ + ((size_t)(b * DM + dm)) * DS);
        #pragma unroll
        for (int r4 = 0; r4 < 4; r4++) {
            f32x4 v = hi[r4];
            #pragma unroll
            for (int q = 0; q < 4; q++) h[r4 * 4 + q] = v[q];
        }
    }

    size_t base = ((size_t)b * L_ + l0) * DM + dm;
    #pragma unroll 4
    for (int j = 0; j < CL; j++) {
        float dl  = delta[base + (size_t)j * DM];
        float xv  = xc[base + (size_t)j * DM];
        float rv  = res[base + (size_t)j * DM];
        float cmn = dl * xv;
        float y = 0.f;
        const f32x4* sB4 = (const f32x4*)(sB + j * DS);
        const f32x4* sC4 = (const f32x4*)(sC + j * DS);
        #pragma unroll
        for (int r4 = 0; r4 < 4; r4++) {
            f32x4 bv = sB4[r4];
            f32x4 cv = sC4[r4];
            #pragma unroll
            for (int q = 0; q < 4; q++) {
                int i = r4 * 4 + q;
                float dA = __expf(dl * Aval[i]);
                h[i] = fmaf(dA, h[i], cmn * bv[q]);
                y = fmaf(h[i], cv[q], y);
            }
        }
        float g = rv / (1.f + __expf(-rv));
        ybar[base + (size_t)j * DM] = (__bf16)((y + Dval * xv) * g);
    }
}

// ---------------------------------------------------------------------------
extern "C" void kernel_launch(void* const* d_in, const int* in_sizes, int n_in,
                              void* d_out, int out_size, void* d_ws, size_t ws_size,
                              hipStream_t stream) {
    // All reference tensors are float32.
    const float* x_in   = (const float*)d_in[0];
    const float* W_in   = (const float*)d_in[1];
    const float* W_res  = (const float*)d_in[2];
    const float* W_out  = (const float*)d_in[3];
    const float* conv_w = (const float*)d_in[4];
    const float* conv_b = (const float*)d_in[5];
    const float* A_log  = (const float*)d_in[6];
    const float* Dw     = (const float*)d_in[7];
    const float* W_B    = (const float*)d_in[8];
    const float* W_C    = (const float*)d_in[9];
    const float* W_dt   = (const float*)d_in[10];
    const float* dt_w   = (const float*)d_in[11];
    const float* dt_b   = (const float*)d_in[12];

    // ---------------- Workspace layout ----------------
    float* ws_f = (float*)d_ws;
    float* x     = ws_f;                        // M_*DM
    float* res   = x     + (size_t)M_ * DM;
    float* xc    = res   + (size_t)M_ * DM;
    float* delta = xc    + (size_t)M_ * DM;
    float* Ppart = delta + (size_t)M_ * DM;     // KSLICES * M_ * NP2 (split-K partials)
    float* Bp    = Ppart + (size_t)KSLICES * M_ * NP2;   // M_*DS
    float* Cp    = Bp    + (size_t)M_ * DS;
    float* aprod = Cp    + (size_t)M_ * DS;     // NC*S_
    float* cend  = aprod + (size_t)NC * S_;     // NC*S_
    float* hinit = cend  + (size_t)NC * S_;     // NC*S_
    __bf16* bf_base = (__bf16*)(hinit + (size_t)NC * S_);
    __bf16* ybar  = bf_base;                    // M_*DM
    __bf16* xinB  = ybar  + (size_t)M_ * DM;    // M_*DIN
    __bf16* WinT  = xinB  + (size_t)M_ * DIN;   // DM*DIN  } adjacent: forms the
    __bf16* WresT = WinT  + (size_t)DM * DIN;   // DM*DIN  } fused (4096 x DIN) BT
    __bf16* WoutT = WresT + (size_t)DM * DIN;   // DIN*DM
    __bf16* xcB   = WoutT + (size_t)DIN * DM;   // M_*DM
    __bf16* projW = xcB   + (size_t)M_ * DM;    // NP2*DM
    __bf16* dtwT  = projW + (size_t)NP2 * DM;   // DM*DR
    __bf16* dtmpB = dtwT  + (size_t)DM * DR;    // M_*DR

    // ---------------- fused operand prep (1 launch) ----------------
    prep_all<<<16640, 256, 0, stream>>>(x_in, W_in, W_res, W_out, dt_w, W_B, W_C, W_dt,
                                        xinB, WinT, WresT, WoutT, dtwT, projW);

    // Fused input GEMMs: [x | res] = x_in @ [W_in | W_res]  (M_ x 4096, K=DIN)
    gemm_tile128<2><<<dim3((2 * DM) / 128, M_ / 128, 1), 256, 0, stream>>>(
        xinB, WinT, x, res, nullptr, M_, 2 * DM, DIN, DIN, DIN);

    conv_silu<<<(M_ * DM) / 256, 256, 0, stream>>>(x, conv_w, conv_b, xc, xcB);

    // Packed projections, split-K: Ppart[ks] = xc @ [W_B|W_C|W_dt|0] slice
    gemm_tile128<0><<<dim3(NP2 / 128, M_ / 128, KSLICES), 256, 0, stream>>>(
        xcB, projW, Ppart, nullptr, nullptr, M_, NP2, KSL, DM, DM);
    reduce_split<<<(M_ * 160) / 256, 256, 0, stream>>>(Ppart, Bp, Cp, dtmpB);

    // delta = softplus(dtmp @ dt_w + dt_b)  (M_ x DM, K=DR)
    gemm_tile128<1><<<dim3(DM / 128, M_ / 128, 1), 256, 0, stream>>>(
        dtmpB, dtwT, delta, nullptr, dt_b, M_, DM, DR, DR, DR);

    // Chunked selective scan
    int nblk = B_ * (DM / 256) * NC;   // 1024
    scan_phase1<<<nblk, 256, 0, stream>>>(delta, xc, Bp, A_log, aprod, cend);
    scan_phase2<<<S_ / 256, 256, 0, stream>>>(aprod, cend, hinit);
    scan_phase3<<<nblk, 256, 0, stream>>>(delta, xc, Bp, Cp, res, A_log, Dw, hinit, ybar);

    // out = ybar @ W_out  (M_ x DIN, K=DM), f32 output
    gemm_tile128<0><<<dim3(DIN / 128, M_ / 128, 1), 256, 0, stream>>>(
        ybar, WoutT, (float*)d_out, nullptr, nullptr, M_, DIN, DM, DM, DM);
}